// Round 2
// baseline (1194.020 us; speedup 1.0000x reference)
//
#include <hip/hip_runtime.h>
#include <math.h>

#ifndef M_PI
#define M_PI 3.14159265358979323846
#endif

typedef unsigned int u32;
typedef unsigned short u16;

#define DEVI __device__ __forceinline__

// ---------------- geometry ----------------
// B=2, E=128, ENC=64, HEADS=4, DH=32, H=W=80, padded 160
constexpr int QD   = 12800 * 128;                 // diag q/k offset (bf16 elems)
constexpr int Q_SZ = 12800 * 128 + 102400 * 128;  // 14,745,600
constexpr int RW_SZ = 2 * 2 * 160 * 160 * 64;     // 6,553,600
constexpr int RC_SZ = 2 * 80 * 80 * 64;           // 819,200

// float region offsets (in floats)
constexpr int F_V80  = 0;       // [4][80][32]
constexpr int F_V160 = 10240;   // [4][160][32]
constexpr int F_S80  = 30720;   // [80][64]
constexpr int F_C80  = 35840;
constexpr int F_S160 = 40960;   // [160][64]
constexpr int F_C160 = 51200;
constexpr int F_WOT  = 61440;   // [128][64]  (WoT[j][e] = Wo[e][j])
constexpr int F_END  = 69632;
constexpr size_t FBYTES = (size_t)F_END * 4;

DEVI float bf2f(u16 h) { return __uint_as_float(((u32)h) << 16); }
DEVI u16 f2bf(float f) {
    u32 u = __float_as_uint(f);
    u32 r = (u + 0x7fffu + ((u >> 16) & 1u)) >> 16;
    return (u16)r;
}
DEVI u32 pack2(float lo, float hi) { return (u32)f2bf(lo) | ((u32)f2bf(hi) << 16); }
DEVI void up2(u32 u, float& lo, float& hi) {
    lo = __uint_as_float(u << 16);
    hi = __uint_as_float(u & 0xffff0000u);
}

// ---------------- K0: PE tables + V tables ----------------
__global__ void k_tables(const float* __restrict__ Wi, const float* __restrict__ bi,
                         float* __restrict__ wsf) {
    int blk = blockIdx.x, t = threadIdx.x;
    int Lsz, l;
    float *vout, *sout, *cout;
    if (blk < 80) { Lsz = 80;  l = blk;      vout = wsf + F_V80;  sout = wsf + F_S80;  cout = wsf + F_C80; }
    else          { Lsz = 160; l = blk - 80; vout = wsf + F_V160; sout = wsf + F_S160; cout = wsf + F_C160; }
    __shared__ float P[128];
    if (t < 64) {
        float dv = powf(10000.f, (float)t / 64.f);
        float X = (float)(l + 1) / dv;
        float sv = sinf(X), cv = cosf(X);
        P[2 * t] = sv; P[2 * t + 1] = cv;
        sout[l * 64 + t] = sv; cout[l * 64 + t] = cv;
    }
    __syncthreads();
    float acc = bi[256 + t];
    #pragma unroll 16
    for (int c = 0; c < 128; ++c) acc += P[c] * Wi[(256 + t) * 128 + c];
    int hh = t >> 5, d = t & 31;
    vout[(hh * Lsz + l) * 32 + d] = acc;
}

// ---------------- transpose Wo (first 64 rows) ----------------
__global__ void k_wot(const float* __restrict__ Wo, float* __restrict__ wsf) {
    int idx = blockIdx.x * 256 + threadIdx.x;
    if (idx < 128 * 64) {
        int e = idx & 63, j = idx >> 6;
        wsf[F_WOT + idx] = Wo[e * 128 + j];
    }
}

// ---------------- K1a: per-pixel Q/K projection (row+col shared) ----------------
__global__ __launch_bounds__(256) void k1_rc(const float* __restrict__ x,
                                             const float* __restrict__ Wi,
                                             const float* __restrict__ bi,
                                             u16* __restrict__ qws, u16* __restrict__ kws) {
    __shared__ float matS[80][17];
    __shared__ float wS[256][17];
    int t = threadIdx.x;
    int blk = blockIdx.x;
    int b = blk / 80, a = blk % 80;
    int pg = t & 15, jg = t >> 4;  // lanes vary pg -> conflict-free matS reads
    float acc[5][16];
    #pragma unroll
    for (int jj = 0; jj < 16; ++jj) {
        float bv = bi[jg * 16 + jj];
        #pragma unroll
        for (int pp = 0; pp < 5; ++pp) acc[pp][jj] = bv;
    }
    for (int c0 = 0; c0 < 128; c0 += 16) {
        for (int idx = t; idx < 80 * 16; idx += 256) {
            int l = idx % 80, cc = idx / 80;
            matS[l][cc] = x[(b * 128 + c0 + cc) * 6400 + a * 80 + l];
        }
        {
            const float* wrow = Wi + t * 128 + c0;
            #pragma unroll
            for (int cc = 0; cc < 16; ++cc) wS[t][cc] = wrow[cc];
        }
        __syncthreads();
        #pragma unroll 4
        for (int cc = 0; cc < 16; ++cc) {
            float m[5];
            #pragma unroll
            for (int pp = 0; pp < 5; ++pp) m[pp] = matS[pg * 5 + pp][cc];
            #pragma unroll
            for (int jj = 0; jj < 16; ++jj) {
                float wv = wS[jg * 16 + jj][cc];
                #pragma unroll
                for (int pp = 0; pp < 5; ++pp) acc[pp][jj] += m[pp] * wv;
            }
        }
        __syncthreads();
    }
    int j0 = jg * 16;
    u16* base = (j0 < 128) ? qws : kws;
    int jb = (j0 < 128) ? j0 : (j0 - 128);
    #pragma unroll
    for (int pp = 0; pp < 5; ++pp) {
        int p = pg * 5 + pp;
        size_t pix = (size_t)(b * 80 + a) * 80 + p;
        u32* dst = (u32*)(base + pix * 128 + jb);
        #pragma unroll
        for (int i = 0; i < 8; ++i) dst[i] = pack2(acc[pp][2 * i], acc[pp][2 * i + 1]);
    }
}

// ---------------- K1b: rotated Q/K projection (bilinear gather) ----------------
DEVI float tapx(const float* plane, int y, int x) {
    return (y >= 40 && y < 120 && x >= 40 && x < 120) ? plane[(y - 40) * 80 + (x - 40)] : 0.f;
}

__global__ __launch_bounds__(256) void k1_diag(const float* __restrict__ x,
                                               const float* __restrict__ Wi,
                                               const float* __restrict__ bi,
                                               u16* __restrict__ qws, u16* __restrict__ kws,
                                               float co, float si) {
    __shared__ float matS[80][17];
    __shared__ float wS[256][17];
    __shared__ int ix0[80], iy0[80];
    __shared__ float fwx[80], fwy[80];
    int t = threadIdx.x;
    int blk = blockIdx.x;
    int rot = blk / 640;
    int r2 = blk % 640;
    int b = r2 / 320;
    int r3 = r2 % 320;
    int a = r3 >> 1;
    int half = r3 & 1;
    int l0 = half * 80;
    float sir = rot ? -si : si;
    if (t < 80) {
        float dxx = (float)(l0 + t) - 79.5f, dyy = (float)a - 79.5f;
        float sx = co * dxx + sir * dyy + 79.5f;
        float sy = -sir * dxx + co * dyy + 79.5f;
        float x0 = floorf(sx), y0 = floorf(sy);
        ix0[t] = (int)x0; iy0[t] = (int)y0;
        fwx[t] = sx - x0; fwy[t] = sy - y0;
    }
    __syncthreads();
    int pg = t & 15, jg = t >> 4;
    float acc[5][16];
    #pragma unroll
    for (int jj = 0; jj < 16; ++jj) {
        float bv = bi[jg * 16 + jj];
        #pragma unroll
        for (int pp = 0; pp < 5; ++pp) acc[pp][jj] = bv;
    }
    for (int c0 = 0; c0 < 128; c0 += 16) {
        for (int idx = t; idx < 80 * 16; idx += 256) {
            int l = idx % 80, cc = idx / 80;
            const float* plane = x + (size_t)(b * 128 + c0 + cc) * 6400;
            int xx0 = ix0[l], yy0 = iy0[l];
            float wx = fwx[l], wy = fwy[l];
            float v00 = tapx(plane, yy0, xx0), v01 = tapx(plane, yy0, xx0 + 1);
            float v10 = tapx(plane, yy0 + 1, xx0), v11 = tapx(plane, yy0 + 1, xx0 + 1);
            matS[l][cc] = (1.f - wy) * ((1.f - wx) * v00 + wx * v01) +
                          wy * ((1.f - wx) * v10 + wx * v11);
        }
        {
            const float* wrow = Wi + t * 128 + c0;
            #pragma unroll
            for (int cc = 0; cc < 16; ++cc) wS[t][cc] = wrow[cc];
        }
        __syncthreads();
        #pragma unroll 4
        for (int cc = 0; cc < 16; ++cc) {
            float m[5];
            #pragma unroll
            for (int pp = 0; pp < 5; ++pp) m[pp] = matS[pg * 5 + pp][cc];
            #pragma unroll
            for (int jj = 0; jj < 16; ++jj) {
                float wv = wS[jg * 16 + jj][cc];
                #pragma unroll
                for (int pp = 0; pp < 5; ++pp) acc[pp][jj] += m[pp] * wv;
            }
        }
        __syncthreads();
    }
    int seqd = (rot * 2 + b) * 160 + a;
    size_t rowbase = (size_t)QD + (size_t)seqd * 160 * 128;
    int j0 = jg * 16;
    u16* base = (j0 < 128) ? qws : kws;
    int jb = (j0 < 128) ? j0 : (j0 - 128);
    #pragma unroll
    for (int pp = 0; pp < 5; ++pp) {
        int p = l0 + pg * 5 + pp;
        u32* dst = (u32*)(base + rowbase + (size_t)p * 128 + jb);
        #pragma unroll
        for (int i = 0; i < 8; ++i) dst[i] = pack2(acc[pp][2 * i], acc[pp][2 * i + 1]);
    }
}

// ---------------- K2: fused attention (one block per sequence) ----------------
// VAR=0: row+col (L=80, grid 320); VAR=1: diag (L=160, grid 640)
template <int VAR>
__global__ __launch_bounds__(256) void k_att(const u16* __restrict__ qws,
                                             const u16* __restrict__ kws,
                                             const float* __restrict__ wsf,
                                             const float* __restrict__ bo,
                                             u16* __restrict__ rowres, u16* __restrict__ colres,
                                             u16* __restrict__ rws, float co, float si) {
    constexpr int L = VAR ? 160 : 80;
    __shared__ uint4 kSq[L * 16];        // [L][128] bf16
    __shared__ u32 oSu[64 * 65];         // [64][130] bf16 (padded)
    int t = threadIdx.x;
    int lane = t & 63;
    int hh = __builtin_amdgcn_readfirstlane(t >> 6);
    int blk = blockIdx.x;
    int b = 0, a = 0, isCol = 0, rot = 0, seqd = 0;
    if (VAR == 0) {
        isCol = (blk >= 160) ? 1 : 0;
        int r = blk - isCol * 160;
        b = r / 80; a = r % 80;
    } else {
        rot = blk / 320;
        int r = blk % 320;
        b = r / 160; a = r % 160;
        seqd = (rot * 2 + b) * 160 + a;
    }
    // stage K into LDS
    if (VAR == 1) {
        const uint4* src = (const uint4*)(kws + (size_t)QD + (size_t)seqd * 160 * 128);
        for (int i = t; i < 160 * 16; i += 256) kSq[i] = src[i];
    } else if (!isCol) {
        const uint4* src = (const uint4*)(kws + (size_t)((b * 80 + a) * 80) * 128);
        for (int i = t; i < 80 * 16; i += 256) kSq[i] = src[i];
    } else {
        for (int i = t; i < 80 * 16; i += 256) {
            int l = i >> 4, u = i & 15;
            kSq[i] = ((const uint4*)(kws + (size_t)((b * 80 + l) * 80 + a) * 128))[u];
        }
    }
    __syncthreads();
    const float* vbase = wsf + (VAR ? F_V160 : F_V80) + hh * L * 32;
    const float* sinT = wsf + (VAR ? F_S160 : F_S80);
    const float* cosT = wsf + (VAR ? F_C160 : F_C80);
    const float* WoT = wsf + F_WOT;
    float sir = (VAR && rot) ? -si : si;
    float dyy = (float)a - 79.5f;
    const float rs = 0.17677669529663687f;  // 1/sqrt(32)

    for (int c0 = 0; c0 < L; c0 += 64) {
        int l = c0 + lane;
        bool act = l < L;
        int lq = act ? l : (L - 1);
        size_t qoff;
        if (VAR) qoff = (size_t)QD + (size_t)(seqd * 160 + lq) * 128;
        else if (isCol) qoff = (size_t)((b * 80 + lq) * 80 + a) * 128;
        else qoff = (size_t)((b * 80 + a) * 80 + lq) * 128;
        const uint4* qp = (const uint4*)(qws + qoff + hh * 32);
        float q[32];
        {
            uint4 w0 = qp[0], w1 = qp[1], w2 = qp[2], w3 = qp[3];
            u32 ww[16] = {w0.x, w0.y, w0.z, w0.w, w1.x, w1.y, w1.z, w1.w,
                          w2.x, w2.y, w2.z, w2.w, w3.x, w3.y, w3.z, w3.w};
            #pragma unroll
            for (int i = 0; i < 16; ++i) {
                float lo, hi; up2(ww[i], lo, hi);
                q[2 * i] = lo * rs; q[2 * i + 1] = hi * rs;
            }
        }
        float o[32];
        #pragma unroll
        for (int d = 0; d < 32; ++d) o[d] = 0.f;
        float mrun = -3.0e38f, ssum = 0.f;
        for (int m = 0; m < L; ++m) {
            const uint4* kr = kSq + m * 16 + hh * 4;
            uint4 kk0 = kr[0], kk1 = kr[1], kk2 = kr[2], kk3 = kr[3];
            u32 kw[16] = {kk0.x, kk0.y, kk0.z, kk0.w, kk1.x, kk1.y, kk1.z, kk1.w,
                          kk2.x, kk2.y, kk2.z, kk2.w, kk3.x, kk3.y, kk3.z, kk3.w};
            float s = 0.f;
            #pragma unroll
            for (int i = 0; i < 16; ++i) {
                float lo, hi; up2(kw[i], lo, hi);
                s += q[2 * i] * lo + q[2 * i + 1] * hi;
            }
            if (VAR) {  // analytic rotated mask bias (nearest, half-even like jnp.round)
                float dxm = (float)m - 79.5f;
                float sx = co * dxm + sir * dyy + 79.5f;
                float sy = -sir * dxm + co * dyy + 79.5f;
                int xi = (int)rintf(sx), yi = (int)rintf(sy);
                if (xi >= 40 && xi < 120 && yi >= 40 && yi < 120) s += 1.0f;
            }
            float p;
            if (s > mrun + 8.f) {  // defer-max: rescale only on big jumps
                float corr = __expf(mrun - s);
                ssum *= corr;
                #pragma unroll
                for (int d = 0; d < 32; ++d) o[d] *= corr;
                mrun = s;
                p = 1.f;
            } else {
                p = __expf(s - mrun);
            }
            ssum += p;
            const float* vr = vbase + m * 32;
            #pragma unroll
            for (int d = 0; d < 32; ++d) o[d] += p * vr[d];
        }
        float inv = 1.f / ssum;
        if (act) {
            #pragma unroll
            for (int i = 0; i < 16; ++i)
                oSu[lane * 65 + hh * 16 + i] = pack2(o[2 * i] * inv, o[2 * i + 1] * inv);
        }
        __syncthreads();
        // epilogue: oo = o @ WoT + bo ; relative rotation ; store bf16
        int CL = (L - c0 < 64) ? (L - c0) : 64;
        int e = lane;
        int lw = t >> 6;
        for (int li = 0; li < 16; ++li) {
            int lp = lw * 16 + li;
            if (lp >= CL) break;
            float acc = bo[e];
            #pragma unroll 8
            for (int jw = 0; jw < 64; ++jw) {
                float lo, hi; up2(oSu[lp * 65 + jw], lo, hi);
                acc += lo * WoT[(2 * jw) * 64 + e] + hi * WoT[(2 * jw + 1) * 64 + e];
            }
            int lg = c0 + lp;
            float sn = sinT[lg * 64 + (e >> 1)], cs = cosT[lg * 64 + (e >> 1)];
            float part = __shfl_xor(acc, 1);
            float r = (e & 1) ? (acc * cs + part * sn) : (acc * cs - part * sn);
            u16* dst;
            if (VAR) dst = rws + (size_t)((((rot * 2 + b) * 160 + a) * 160 + lg)) * 64;
            else if (isCol) dst = colres + (size_t)(((b * 80 + lg) * 80 + a)) * 64;
            else dst = rowres + (size_t)(((b * 80 + a) * 80 + lg)) * 64;
            dst[e] = f2bf(r);
        }
        __syncthreads();
    }
}

// ---------------- K3: rotate-back + elementwise sort + assemble ----------------
__global__ __launch_bounds__(256) void k3(const u16* __restrict__ rowres,
                                          const u16* __restrict__ colres,
                                          const u16* __restrict__ rws,
                                          float* __restrict__ out, float co, float si) {
    __shared__ float buf[40][257];
    int t = threadIdx.x;
    int blk = blockIdx.x;
    int b = blk / 160;
    int rem = blk % 160;
    int h = rem >> 1;
    int half = rem & 1;
    int w0 = half * 40;
    int e = t & 63, wv = t >> 6;
    for (int k = 0; k < 10; ++k) {
        int wl = wv * 10 + k;
        int w = w0 + wl;
        size_t pix = (size_t)(b * 80 + h) * 80 + w;
        float v0 = bf2f(rowres[pix * 64 + e]);
        float v1 = bf2f(colres[pix * 64 + e]);
        float dxx = (float)(w + 40) - 79.5f, dyy = (float)(h + 40) - 79.5f;
        float dvals[2];
        #pragma unroll
        for (int r = 0; r < 2; ++r) {
            float sirb = r ? si : -si;  // rotate-back angle = -ang
            float sx = co * dxx + sirb * dyy + 79.5f;
            float sy = -sirb * dxx + co * dyy + 79.5f;
            float x0 = floorf(sx), y0 = floorf(sy);
            int xi = (int)x0, yi = (int)y0;
            float wx = sx - x0, wy = sy - y0;
            const u16* rb = rws + (size_t)((r * 2 + b) * 160) * 160 * 64;
            float t00 = (yi >= 0 && yi < 160 && xi >= 0 && xi < 160) ? bf2f(rb[((size_t)yi * 160 + xi) * 64 + e]) : 0.f;
            float t01 = (yi >= 0 && yi < 160 && xi + 1 >= 0 && xi + 1 < 160) ? bf2f(rb[((size_t)yi * 160 + xi + 1) * 64 + e]) : 0.f;
            float t10 = (yi + 1 >= 0 && yi + 1 < 160 && xi >= 0 && xi < 160) ? bf2f(rb[((size_t)(yi + 1) * 160 + xi) * 64 + e]) : 0.f;
            float t11 = (yi + 1 >= 0 && yi + 1 < 160 && xi + 1 >= 0 && xi + 1 < 160) ? bf2f(rb[((size_t)(yi + 1) * 160 + xi + 1) * 64 + e]) : 0.f;
            dvals[r] = (1.f - wy) * ((1.f - wx) * t00 + wx * t01) + wy * ((1.f - wx) * t10 + wx * t11);
        }
        float a0 = v0, a1 = v1, a2 = dvals[0], a3 = dvals[1];
        float mn, mx;
        mn = fminf(a0, a1); mx = fmaxf(a0, a1); a0 = mn; a1 = mx;
        mn = fminf(a2, a3); mx = fmaxf(a2, a3); a2 = mn; a3 = mx;
        mn = fminf(a0, a2); mx = fmaxf(a0, a2); a0 = mn; a2 = mx;
        mn = fminf(a1, a3); mx = fmaxf(a1, a3); a1 = mn; a3 = mx;
        mn = fminf(a1, a2); mx = fmaxf(a1, a2); a1 = mn; a2 = mx;
        buf[wl][0 * 64 + e] = a0;
        buf[wl][1 * 64 + e] = a1;
        buf[wl][2 * 64 + e] = a2;
        buf[wl][3 * 64 + e] = a3;
    }
    __syncthreads();
    for (int idx = t; idx < 256 * 40; idx += 256) {
        int c = idx / 40, wl = idx % 40;
        out[(size_t)((b * 384 + 128 + c) * 80 + h) * 80 + w0 + wl] = buf[wl][c];
    }
}

// ---------------- x passthrough (channels 0..127) ----------------
__global__ void k_copy(const float* __restrict__ x, float* __restrict__ out) {
    int idx = blockIdx.x * 256 + threadIdx.x;
    if (idx < 409600) {
        float4 v = ((const float4*)x)[idx];
        int b = idx / 204800;
        int rem = idx % 204800;
        ((float4*)out)[(size_t)b * 614400 + rem] = v;
    }
}

extern "C" void kernel_launch(void* const* d_in, const int* in_sizes, int n_in,
                              void* d_out, int out_size, void* d_ws, size_t ws_size,
                              hipStream_t stream) {
    (void)in_sizes; (void)n_in; (void)out_size;
    const float* x  = (const float*)d_in[0];
    const float* Wi = (const float*)d_in[1];
    const float* bi = (const float*)d_in[2];
    const float* Wo = (const float*)d_in[3];
    const float* bo = (const float*)d_in[4];
    float* out = (float*)d_out;

    float* wsf = (float*)d_ws;
    u16* wsb = (u16*)((char*)d_ws + FBYTES);
    u16* qws = wsb;
    u16* kws = wsb + (size_t)Q_SZ;
    u16* rws = kws + (size_t)Q_SZ;
    u16* rowres = rws + (size_t)RW_SZ;
    u16* colres = rowres + (size_t)RC_SZ;

    size_t need = FBYTES + ((size_t)Q_SZ * 2 + RW_SZ + RC_SZ * 2) * 2;
    if (ws_size < need) return;  // signals ws shortfall via failed validation

    double th = 45.0 * M_PI / 180.0;
    float co = (float)cos(th), si = (float)sin(th);

    k_tables<<<dim3(240), dim3(128), 0, stream>>>(Wi, bi, wsf);
    k_wot<<<dim3(32), dim3(256), 0, stream>>>(Wo, wsf);
    k1_rc<<<dim3(160), dim3(256), 0, stream>>>(x, Wi, bi, qws, kws);
    k1_diag<<<dim3(1280), dim3(256), 0, stream>>>(x, Wi, bi, qws, kws, co, si);
    k_att<0><<<dim3(320), dim3(256), 0, stream>>>(qws, kws, wsf, bo, rowres, colres, rws, co, si);
    k_att<1><<<dim3(640), dim3(256), 0, stream>>>(qws, kws, wsf, bo, rowres, colres, rws, co, si);
    k3<<<dim3(320), dim3(256), 0, stream>>>(rowres, colres, rws, out, co, si);
    k_copy<<<dim3(1600), dim3(256), 0, stream>>>(x, out);
}

// Round 3
// 581.510 us; speedup vs baseline: 2.0533x; 2.0533x over previous
//
#include <hip/hip_runtime.h>
#include <math.h>

#ifndef M_PI
#define M_PI 3.14159265358979323846
#endif

typedef unsigned int u32;
typedef unsigned short u16;
typedef float f32x2 __attribute__((ext_vector_type(2)));

#define DEVI __device__ __forceinline__

// ---------------- geometry ----------------
// B=2, E=128, ENC=64, HEADS=4, DH=32, H=W=80, padded 160
constexpr int QD   = 12800 * 128;                 // diag q/k offset (bf16 elems)
constexpr int Q_SZ = 12800 * 128 + 102400 * 128;  // 14,745,600
constexpr int RW_SZ = 2 * 2 * 160 * 160 * 64;     // 6,553,600
constexpr int RC_SZ = 2 * 80 * 80 * 64;           // 819,200

// float region offsets (in floats)
constexpr int F_V80  = 0;       // [4][80][32]
constexpr int F_V160 = 10240;   // [4][160][32]
constexpr int F_S80  = 30720;   // [80][64]
constexpr int F_C80  = 35840;
constexpr int F_S160 = 40960;   // [160][64]
constexpr int F_C160 = 51200;
constexpr int F_WOT  = 61440;   // u32 region: [64 pairs j][64 e] packed bf16 (Wo[e][2j],Wo[e][2j+1])
constexpr int F_END  = 69632;
constexpr size_t FBYTES = (size_t)F_END * 4;

DEVI float bf2f(u16 h) { return __uint_as_float(((u32)h) << 16); }
DEVI u16 f2bf(float f) {
    u32 u = __float_as_uint(f);
    u32 r = (u + 0x7fffu + ((u >> 16) & 1u)) >> 16;
    return (u16)r;
}
DEVI u32 pack2(float lo, float hi) { return (u32)f2bf(lo) | ((u32)f2bf(hi) << 16); }
DEVI f32x2 kpair(u32 w) {
    f32x2 r;
    r.x = __uint_as_float(w << 16);
    r.y = __uint_as_float(w & 0xffff0000u);
    return r;
}

// ---------------- K0: PE tables + V tables ----------------
__global__ void k_tables(const float* __restrict__ Wi, const float* __restrict__ bi,
                         float* __restrict__ wsf) {
    int blk = blockIdx.x, t = threadIdx.x;
    int Lsz, l;
    float *vout, *sout, *cout;
    if (blk < 80) { Lsz = 80;  l = blk;      vout = wsf + F_V80;  sout = wsf + F_S80;  cout = wsf + F_C80; }
    else          { Lsz = 160; l = blk - 80; vout = wsf + F_V160; sout = wsf + F_S160; cout = wsf + F_C160; }
    __shared__ float P[128];
    if (t < 64) {
        float dv = powf(10000.f, (float)t / 64.f);
        float X = (float)(l + 1) / dv;
        float sv = sinf(X), cv = cosf(X);
        P[2 * t] = sv; P[2 * t + 1] = cv;
        sout[l * 64 + t] = sv; cout[l * 64 + t] = cv;
    }
    __syncthreads();
    float acc = bi[256 + t];
    #pragma unroll 16
    for (int c = 0; c < 128; ++c) acc += P[c] * Wi[(256 + t) * 128 + c];
    int hh = t >> 5, d = t & 31;
    vout[(hh * Lsz + l) * 32 + d] = acc;
}

// ---------------- pack Wo (first 64 rows) to bf16 pairs ----------------
__global__ void k_wot(const float* __restrict__ Wo, u32* __restrict__ wotp) {
    int idx = blockIdx.x * 256 + threadIdx.x;
    if (idx < 64 * 64) {
        int e = idx & 63, j = idx >> 6;   // j = pair index 0..63
        wotp[j * 64 + e] = pack2(Wo[e * 128 + 2 * j], Wo[e * 128 + 2 * j + 1]);
    }
}

// ---------------- K1a: per-pixel Q/K projection (row+col shared) ----------------
__global__ __launch_bounds__(256) void k1_rc(const float* __restrict__ x,
                                             const float* __restrict__ Wi,
                                             const float* __restrict__ bi,
                                             u16* __restrict__ qws, u16* __restrict__ kws) {
    __shared__ float matS[80][17];
    __shared__ float wS[256][17];
    int t = threadIdx.x;
    int blk = blockIdx.x;
    int b = blk / 80, a = blk % 80;
    int pg = t & 15, jg = t >> 4;
    float acc[5][16];
    #pragma unroll
    for (int jj = 0; jj < 16; ++jj) {
        float bv = bi[jg * 16 + jj];
        #pragma unroll
        for (int pp = 0; pp < 5; ++pp) acc[pp][jj] = bv;
    }
    for (int c0 = 0; c0 < 128; c0 += 16) {
        for (int idx = t; idx < 80 * 16; idx += 256) {
            int l = idx % 80, cc = idx / 80;
            matS[l][cc] = x[(b * 128 + c0 + cc) * 6400 + a * 80 + l];
        }
        {
            const float* wrow = Wi + t * 128 + c0;
            #pragma unroll
            for (int cc = 0; cc < 16; ++cc) wS[t][cc] = wrow[cc];
        }
        __syncthreads();
        #pragma unroll 4
        for (int cc = 0; cc < 16; ++cc) {
            float m[5];
            #pragma unroll
            for (int pp = 0; pp < 5; ++pp) m[pp] = matS[pg * 5 + pp][cc];
            #pragma unroll
            for (int jj = 0; jj < 16; ++jj) {
                float wv = wS[jg * 16 + jj][cc];
                #pragma unroll
                for (int pp = 0; pp < 5; ++pp) acc[pp][jj] += m[pp] * wv;
            }
        }
        __syncthreads();
    }
    int j0 = jg * 16;
    u16* base = (j0 < 128) ? qws : kws;
    int jb = (j0 < 128) ? j0 : (j0 - 128);
    #pragma unroll
    for (int pp = 0; pp < 5; ++pp) {
        int p = pg * 5 + pp;
        size_t pix = (size_t)(b * 80 + a) * 80 + p;
        u32* dst = (u32*)(base + pix * 128 + jb);
        #pragma unroll
        for (int i = 0; i < 8; ++i) dst[i] = pack2(acc[pp][2 * i], acc[pp][2 * i + 1]);
    }
}

// ---------------- K1b: rotated Q/K projection (bilinear gather) ----------------
DEVI float tapx(const float* plane, int y, int x) {
    return (y >= 40 && y < 120 && x >= 40 && x < 120) ? plane[(y - 40) * 80 + (x - 40)] : 0.f;
}

__global__ __launch_bounds__(256) void k1_diag(const float* __restrict__ x,
                                               const float* __restrict__ Wi,
                                               const float* __restrict__ bi,
                                               u16* __restrict__ qws, u16* __restrict__ kws,
                                               float co, float si) {
    __shared__ float matS[80][17];
    __shared__ float wS[256][17];
    __shared__ int ix0[80], iy0[80];
    __shared__ float fwx[80], fwy[80];
    int t = threadIdx.x;
    int blk = blockIdx.x;
    int rot = blk / 640;
    int r2 = blk % 640;
    int b = r2 / 320;
    int r3 = r2 % 320;
    int a = r3 >> 1;
    int half = r3 & 1;
    int l0 = half * 80;
    float sir = rot ? -si : si;
    if (t < 80) {
        float dxx = (float)(l0 + t) - 79.5f, dyy = (float)a - 79.5f;
        float sx = co * dxx + sir * dyy + 79.5f;
        float sy = -sir * dxx + co * dyy + 79.5f;
        float x0 = floorf(sx), y0 = floorf(sy);
        ix0[t] = (int)x0; iy0[t] = (int)y0;
        fwx[t] = sx - x0; fwy[t] = sy - y0;
    }
    __syncthreads();
    int pg = t & 15, jg = t >> 4;
    float acc[5][16];
    #pragma unroll
    for (int jj = 0; jj < 16; ++jj) {
        float bv = bi[jg * 16 + jj];
        #pragma unroll
        for (int pp = 0; pp < 5; ++pp) acc[pp][jj] = bv;
    }
    for (int c0 = 0; c0 < 128; c0 += 16) {
        for (int idx = t; idx < 80 * 16; idx += 256) {
            int l = idx % 80, cc = idx / 80;
            const float* plane = x + (size_t)(b * 128 + c0 + cc) * 6400;
            int xx0 = ix0[l], yy0 = iy0[l];
            float wx = fwx[l], wy = fwy[l];
            float v00 = tapx(plane, yy0, xx0), v01 = tapx(plane, yy0, xx0 + 1);
            float v10 = tapx(plane, yy0 + 1, xx0), v11 = tapx(plane, yy0 + 1, xx0 + 1);
            matS[l][cc] = (1.f - wy) * ((1.f - wx) * v00 + wx * v01) +
                          wy * ((1.f - wx) * v10 + wx * v11);
        }
        {
            const float* wrow = Wi + t * 128 + c0;
            #pragma unroll
            for (int cc = 0; cc < 16; ++cc) wS[t][cc] = wrow[cc];
        }
        __syncthreads();
        #pragma unroll 4
        for (int cc = 0; cc < 16; ++cc) {
            float m[5];
            #pragma unroll
            for (int pp = 0; pp < 5; ++pp) m[pp] = matS[pg * 5 + pp][cc];
            #pragma unroll
            for (int jj = 0; jj < 16; ++jj) {
                float wv = wS[jg * 16 + jj][cc];
                #pragma unroll
                for (int pp = 0; pp < 5; ++pp) acc[pp][jj] += m[pp] * wv;
            }
        }
        __syncthreads();
    }
    int seqd = (rot * 2 + b) * 160 + a;
    size_t rowbase = (size_t)QD + (size_t)seqd * 160 * 128;
    int j0 = jg * 16;
    u16* base = (j0 < 128) ? qws : kws;
    int jb = (j0 < 128) ? j0 : (j0 - 128);
    #pragma unroll
    for (int pp = 0; pp < 5; ++pp) {
        int p = l0 + pg * 5 + pp;
        u32* dst = (u32*)(base + rowbase + (size_t)p * 128 + jb);
        #pragma unroll
        for (int i = 0; i < 8; ++i) dst[i] = pack2(acc[pp][2 * i], acc[pp][2 * i + 1]);
    }
}

// ---------------- K2: fused attention, chunk-split, no K-LDS ----------------
// grid: x = chunk (VAR=0: 2, VAR=1: 3), y = seq (VAR=0: 320, VAR=1: 640)
template <int VAR>
__global__ __launch_bounds__(256) void k_att(const u16* __restrict__ qws,
                                             const u16* __restrict__ kws,
                                             const float* __restrict__ wsf,
                                             const u32* __restrict__ wotp,
                                             const float* __restrict__ bo,
                                             u16* __restrict__ rowres, u16* __restrict__ colres,
                                             u16* __restrict__ rws, float co, float si) {
    constexpr int L = VAR ? 160 : 80;
    __shared__ float oS[64 * 130];    // [64 rows][130] f32 (4 heads x 32 + pad)
    __shared__ float biasS[160];
    int t = threadIdx.x;
    int lane = t & 63;
    int hh = __builtin_amdgcn_readfirstlane(t >> 6);
    int chunk = blockIdx.x;
    int seq = blockIdx.y;
    int c0 = chunk * 64;
    int CL = (L - c0 < 64) ? (L - c0) : 64;

    int b = 0, a = 0, isCol = 0, rot = 0, seqd = 0;
    if (VAR == 0) {
        isCol = (seq >= 160) ? 1 : 0;
        int r = seq - isCol * 160;
        b = r / 80; a = r % 80;
    } else {
        rot = seq / 320;
        int r = seq % 320;
        b = r / 160; a = r % 160;
        seqd = (rot * 2 + b) * 160 + a;
    }

    // precompute mask bias (uniform over q-lanes; depends only on key index m)
    if (VAR == 1) {
        float sir = rot ? -si : si;
        float dyy = (float)a - 79.5f;
        if (t < 160) {
            float dxm = (float)t - 79.5f;
            float sx = co * dxm + sir * dyy + 79.5f;
            float sy = -sir * dxm + co * dyy + 79.5f;
            int xi = (int)rintf(sx), yi = (int)rintf(sy);
            biasS[t] = (xi >= 40 && xi < 120 && yi >= 40 && yi < 120) ? 1.0f : 0.0f;
        }
        __syncthreads();
    }

    // K addressing (global; wave-uniform address -> broadcast, L1/L2-served)
    const u16* kb;
    int kstep;
    if (VAR) { kb = kws + (size_t)QD + (size_t)seqd * 160 * 128 + hh * 32; kstep = 128; }
    else if (isCol) { kb = kws + (size_t)(b * 80 * 80 + a) * 128 + hh * 32; kstep = 80 * 128; }
    else { kb = kws + (size_t)((b * 80 + a) * 80) * 128 + hh * 32; kstep = 128; }

    // load my q row (packed bf16 -> f32x2 pairs, unscaled)
    int l = c0 + lane;
    bool act = l < L;
    int lq = act ? l : (L - 1);
    size_t qoff;
    if (VAR) qoff = (size_t)QD + (size_t)(seqd * 160 + lq) * 128;
    else if (isCol) qoff = (size_t)((b * 80 + lq) * 80 + a) * 128;
    else qoff = (size_t)((b * 80 + a) * 80 + lq) * 128;
    f32x2 q2[16];
    {
        const uint4* qp = (const uint4*)(qws + qoff + hh * 32);
        uint4 w0 = qp[0], w1 = qp[1], w2 = qp[2], w3 = qp[3];
        u32 ww[16] = {w0.x, w0.y, w0.z, w0.w, w1.x, w1.y, w1.z, w1.w,
                      w2.x, w2.y, w2.z, w2.w, w3.x, w3.y, w3.z, w3.w};
        #pragma unroll
        for (int i = 0; i < 16; ++i) q2[i] = kpair(ww[i]);
    }

    const float* vbase = wsf + (VAR ? F_V160 : F_V80) + hh * L * 32;
    const float rs = 0.17677669529663687f;  // 1/sqrt(32)

    f32x2 o2[16];
    #pragma unroll
    for (int d = 0; d < 16; ++d) o2[d] = (f32x2){0.f, 0.f};
    float mrun = -3.0e38f, ssum = 0.f;

    uint4 kc0, kc1, kc2, kc3;
    {
        const uint4* kp = (const uint4*)kb;
        kc0 = kp[0]; kc1 = kp[1]; kc2 = kp[2]; kc3 = kp[3];
    }
    for (int m = 0; m < L; ++m) {
        uint4 kn0, kn1, kn2, kn3;
        if (m + 1 < L) {
            const uint4* kp = (const uint4*)(kb + (size_t)(m + 1) * kstep);
            kn0 = kp[0]; kn1 = kp[1]; kn2 = kp[2]; kn3 = kp[3];
        }
        u32 kw[16] = {kc0.x, kc0.y, kc0.z, kc0.w, kc1.x, kc1.y, kc1.z, kc1.w,
                      kc2.x, kc2.y, kc2.z, kc2.w, kc3.x, kc3.y, kc3.z, kc3.w};
        f32x2 s2 = (f32x2){0.f, 0.f};
        #pragma unroll
        for (int i = 0; i < 16; ++i) s2 += kpair(kw[i]) * q2[i];
        float s = (s2.x + s2.y) * rs;
        if (VAR) s += biasS[m];

        float p;
        if (s > mrun + 8.f) {  // defer-max
            float corr = __expf(mrun - s);
            f32x2 corr2 = (f32x2){corr, corr};
            ssum *= corr;
            #pragma unroll
            for (int d = 0; d < 16; ++d) o2[d] *= corr2;
            mrun = s;
            p = 1.f;
        } else {
            p = __expf(s - mrun);
        }
        ssum += p;
        const float4* vr4 = (const float4*)(vbase + (size_t)m * 32);
        f32x2 pv = (f32x2){p, p};
        #pragma unroll
        for (int i = 0; i < 8; ++i) {
            float4 vv = vr4[i];
            o2[2 * i]     += pv * (f32x2){vv.x, vv.y};
            o2[2 * i + 1] += pv * (f32x2){vv.z, vv.w};
        }
        kc0 = kn0; kc1 = kn1; kc2 = kn2; kc3 = kn3;
    }
    float inv = 1.f / ssum;
    if (act) {
        f32x2 inv2 = (f32x2){inv, inv};
        f32x2* dst = (f32x2*)(oS + lane * 130 + hh * 32);
        #pragma unroll
        for (int d = 0; d < 16; ++d) dst[d] = o2[d] * inv2;
    }
    __syncthreads();

    // epilogue: oo = o @ WoT + bo ; relative rotation ; store bf16
    const float* sinT = wsf + (VAR ? F_S160 : F_S80);
    const float* cosT = wsf + (VAR ? F_C160 : F_C80);
    int e = lane;
    int lw = t >> 6;
    for (int li = 0; li < 16; ++li) {
        int lp = lw * 16 + li;
        if (lp >= CL) break;
        f32x2 acc2 = (f32x2){bo[e], 0.f};
        const f32x2* orow = (const f32x2*)(oS + lp * 130);
        #pragma unroll 8
        for (int jw = 0; jw < 64; ++jw) {
            acc2 += orow[jw] * kpair(wotp[jw * 64 + e]);
        }
        float acc = acc2.x + acc2.y;
        int lg = c0 + lp;
        float sn = sinT[lg * 64 + (e >> 1)], cs = cosT[lg * 64 + (e >> 1)];
        float part = __shfl_xor(acc, 1);
        float r = (e & 1) ? (acc * cs + part * sn) : (acc * cs - part * sn);
        u16* dst;
        if (VAR) dst = rws + (size_t)((((rot * 2 + b) * 160 + a) * 160 + lg)) * 64;
        else if (isCol) dst = colres + (size_t)(((b * 80 + lg) * 80 + a)) * 64;
        else dst = rowres + (size_t)(((b * 80 + a) * 80 + lg)) * 64;
        dst[e] = f2bf(r);
    }
}

// ---------------- K3: rotate-back + elementwise sort + assemble ----------------
__global__ __launch_bounds__(256) void k3(const u16* __restrict__ rowres,
                                          const u16* __restrict__ colres,
                                          const u16* __restrict__ rws,
                                          float* __restrict__ out, float co, float si) {
    __shared__ float buf[40][257];
    int t = threadIdx.x;
    int blk = blockIdx.x;
    int b = blk / 160;
    int rem = blk % 160;
    int h = rem >> 1;
    int half = rem & 1;
    int w0 = half * 40;
    int e = t & 63, wv = t >> 6;
    for (int k = 0; k < 10; ++k) {
        int wl = wv * 10 + k;
        int w = w0 + wl;
        size_t pix = (size_t)(b * 80 + h) * 80 + w;
        float v0 = bf2f(rowres[pix * 64 + e]);
        float v1 = bf2f(colres[pix * 64 + e]);
        float dxx = (float)(w + 40) - 79.5f, dyy = (float)(h + 40) - 79.5f;
        float dvals[2];
        #pragma unroll
        for (int r = 0; r < 2; ++r) {
            float sirb = r ? si : -si;  // rotate-back angle = -ang
            float sx = co * dxx + sirb * dyy + 79.5f;
            float sy = -sirb * dxx + co * dyy + 79.5f;
            float x0 = floorf(sx), y0 = floorf(sy);
            int xi = (int)x0, yi = (int)y0;
            float wx = sx - x0, wy = sy - y0;
            const u16* rb = rws + (size_t)((r * 2 + b) * 160) * 160 * 64;
            float t00 = (yi >= 0 && yi < 160 && xi >= 0 && xi < 160) ? bf2f(rb[((size_t)yi * 160 + xi) * 64 + e]) : 0.f;
            float t01 = (yi >= 0 && yi < 160 && xi + 1 >= 0 && xi + 1 < 160) ? bf2f(rb[((size_t)yi * 160 + xi + 1) * 64 + e]) : 0.f;
            float t10 = (yi + 1 >= 0 && yi + 1 < 160 && xi >= 0 && xi < 160) ? bf2f(rb[((size_t)(yi + 1) * 160 + xi) * 64 + e]) : 0.f;
            float t11 = (yi + 1 >= 0 && yi + 1 < 160 && xi + 1 >= 0 && xi + 1 < 160) ? bf2f(rb[((size_t)(yi + 1) * 160 + xi + 1) * 64 + e]) : 0.f;
            dvals[r] = (1.f - wy) * ((1.f - wx) * t00 + wx * t01) + wy * ((1.f - wx) * t10 + wx * t11);
        }
        float a0 = v0, a1 = v1, a2 = dvals[0], a3 = dvals[1];
        float mn, mx;
        mn = fminf(a0, a1); mx = fmaxf(a0, a1); a0 = mn; a1 = mx;
        mn = fminf(a2, a3); mx = fmaxf(a2, a3); a2 = mn; a3 = mx;
        mn = fminf(a0, a2); mx = fmaxf(a0, a2); a0 = mn; a2 = mx;
        mn = fminf(a1, a3); mx = fmaxf(a1, a3); a1 = mn; a3 = mx;
        mn = fminf(a1, a2); mx = fmaxf(a1, a2); a1 = mn; a2 = mx;
        buf[wl][0 * 64 + e] = a0;
        buf[wl][1 * 64 + e] = a1;
        buf[wl][2 * 64 + e] = a2;
        buf[wl][3 * 64 + e] = a3;
    }
    __syncthreads();
    for (int idx = t; idx < 256 * 40; idx += 256) {
        int c = idx / 40, wl = idx % 40;
        out[(size_t)((b * 384 + 128 + c) * 80 + h) * 80 + w0 + wl] = buf[wl][c];
    }
}

// ---------------- x passthrough (channels 0..127) ----------------
__global__ void k_copy(const float* __restrict__ x, float* __restrict__ out) {
    int idx = blockIdx.x * 256 + threadIdx.x;
    if (idx < 409600) {
        float4 v = ((const float4*)x)[idx];
        int b = idx / 204800;
        int rem = idx % 204800;
        ((float4*)out)[(size_t)b * 614400 + rem] = v;
    }
}

extern "C" void kernel_launch(void* const* d_in, const int* in_sizes, int n_in,
                              void* d_out, int out_size, void* d_ws, size_t ws_size,
                              hipStream_t stream) {
    (void)in_sizes; (void)n_in; (void)out_size;
    const float* x  = (const float*)d_in[0];
    const float* Wi = (const float*)d_in[1];
    const float* bi = (const float*)d_in[2];
    const float* Wo = (const float*)d_in[3];
    const float* bo = (const float*)d_in[4];
    float* out = (float*)d_out;

    float* wsf = (float*)d_ws;
    u32* wotp = (u32*)(wsf + F_WOT);
    u16* wsb = (u16*)((char*)d_ws + FBYTES);
    u16* qws = wsb;
    u16* kws = wsb + (size_t)Q_SZ;
    u16* rws = kws + (size_t)Q_SZ;
    u16* rowres = rws + (size_t)RW_SZ;
    u16* colres = rowres + (size_t)RC_SZ;

    size_t need = FBYTES + ((size_t)Q_SZ * 2 + RW_SZ + RC_SZ * 2) * 2;
    if (ws_size < need) return;

    double th = 45.0 * M_PI / 180.0;
    float co = (float)cos(th), si = (float)sin(th);

    k_tables<<<dim3(240), dim3(128), 0, stream>>>(Wi, bi, wsf);
    k_wot<<<dim3(16), dim3(256), 0, stream>>>(Wo, wotp);
    k1_rc<<<dim3(160), dim3(256), 0, stream>>>(x, Wi, bi, qws, kws);
    k1_diag<<<dim3(1280), dim3(256), 0, stream>>>(x, Wi, bi, qws, kws, co, si);
    k_att<0><<<dim3(2, 320), dim3(256), 0, stream>>>(qws, kws, wsf, wotp, bo, rowres, colres, rws, co, si);
    k_att<1><<<dim3(3, 640), dim3(256), 0, stream>>>(qws, kws, wsf, wotp, bo, rowres, colres, rws, co, si);
    k3<<<dim3(320), dim3(256), 0, stream>>>(rowres, colres, rws, out, co, si);
    k_copy<<<dim3(1600), dim3(256), 0, stream>>>(x, out);
}

// Round 4
// 519.991 us; speedup vs baseline: 2.2962x; 1.1183x over previous
//
#include <hip/hip_runtime.h>
#include <math.h>

#ifndef M_PI
#define M_PI 3.14159265358979323846
#endif

typedef unsigned int u32;
typedef unsigned short u16;
typedef float f32x2 __attribute__((ext_vector_type(2)));

#define DEVI __device__ __forceinline__

// ---------------- geometry ----------------
// B=2, E=128, ENC=64, HEADS=4, DH=32, H=W=80, padded 160
constexpr int QD   = 12800 * 128;                 // diag q/k offset (bf16 elems)
constexpr int Q_SZ = 12800 * 128 + 102400 * 128;  // 14,745,600
constexpr int RW_SZ = 2 * 2 * 160 * 160 * 64;     // 6,553,600
constexpr int RC_SZ = 2 * 80 * 80 * 64;           // 819,200

// float region offsets (in floats)
constexpr int F_V80  = 0;       // [4][80][32]
constexpr int F_V160 = 10240;   // [4][160][32]
constexpr int F_S80  = 30720;   // [80][64]
constexpr int F_C80  = 35840;
constexpr int F_S160 = 40960;   // [160][64]
constexpr int F_C160 = 51200;
constexpr int F_WOT  = 61440;   // u32 region: [64 pairs j][64 e] packed bf16 (Wo[e][2j],Wo[e][2j+1])
constexpr int F_END  = 69632;
constexpr size_t FBYTES = (size_t)F_END * 4;

DEVI float bf2f(u16 h) { return __uint_as_float(((u32)h) << 16); }
DEVI u16 f2bf(float f) {
    u32 u = __float_as_uint(f);
    u32 r = (u + 0x7fffu + ((u >> 16) & 1u)) >> 16;
    return (u16)r;
}
DEVI u32 pack2(float lo, float hi) { return (u32)f2bf(lo) | ((u32)f2bf(hi) << 16); }
DEVI f32x2 kpair(u32 w) {
    f32x2 r;
    r.x = __uint_as_float(w << 16);
    r.y = __uint_as_float(w & 0xffff0000u);
    return r;
}

// ---------------- K0: PE tables + V tables ----------------
__global__ void k_tables(const float* __restrict__ Wi, const float* __restrict__ bi,
                         float* __restrict__ wsf) {
    int blk = blockIdx.x, t = threadIdx.x;
    int Lsz, l;
    float *vout, *sout, *cout;
    if (blk < 80) { Lsz = 80;  l = blk;      vout = wsf + F_V80;  sout = wsf + F_S80;  cout = wsf + F_C80; }
    else          { Lsz = 160; l = blk - 80; vout = wsf + F_V160; sout = wsf + F_S160; cout = wsf + F_C160; }
    __shared__ float P[128];
    if (t < 64) {
        float dv = powf(10000.f, (float)t / 64.f);
        float X = (float)(l + 1) / dv;
        float sv = sinf(X), cv = cosf(X);
        P[2 * t] = sv; P[2 * t + 1] = cv;
        sout[l * 64 + t] = sv; cout[l * 64 + t] = cv;
    }
    __syncthreads();
    float acc = bi[256 + t];
    #pragma unroll 16
    for (int c = 0; c < 128; ++c) acc += P[c] * Wi[(256 + t) * 128 + c];
    int hh = t >> 5, d = t & 31;
    vout[(hh * Lsz + l) * 32 + d] = acc;
}

// ---------------- pack Wo (first 64 rows) to bf16 pairs ----------------
__global__ void k_wot(const float* __restrict__ Wo, u32* __restrict__ wotp) {
    int idx = blockIdx.x * 256 + threadIdx.x;
    if (idx < 64 * 64) {
        int e = idx & 63, j = idx >> 6;   // j = pair index 0..63
        wotp[j * 64 + e] = pack2(Wo[e * 128 + 2 * j], Wo[e * 128 + 2 * j + 1]);
    }
}

// ---------------- K1a: per-pixel Q/K projection (row+col shared) ----------------
__global__ __launch_bounds__(256) void k1_rc(const float* __restrict__ x,
                                             const float* __restrict__ Wi,
                                             const float* __restrict__ bi,
                                             u16* __restrict__ qws, u16* __restrict__ kws) {
    __shared__ float matS[80][17];
    __shared__ float wS[256][17];
    int t = threadIdx.x;
    int blk = blockIdx.x;
    int b = blk / 80, a = blk % 80;
    int pg = t & 15, jg = t >> 4;
    float acc[5][16];
    #pragma unroll
    for (int jj = 0; jj < 16; ++jj) {
        float bv = bi[jg * 16 + jj];
        #pragma unroll
        for (int pp = 0; pp < 5; ++pp) acc[pp][jj] = bv;
    }
    for (int c0 = 0; c0 < 128; c0 += 16) {
        for (int idx = t; idx < 80 * 16; idx += 256) {
            int l = idx % 80, cc = idx / 80;
            matS[l][cc] = x[(b * 128 + c0 + cc) * 6400 + a * 80 + l];
        }
        {
            const float* wrow = Wi + t * 128 + c0;
            #pragma unroll
            for (int cc = 0; cc < 16; ++cc) wS[t][cc] = wrow[cc];
        }
        __syncthreads();
        #pragma unroll 4
        for (int cc = 0; cc < 16; ++cc) {
            float m[5];
            #pragma unroll
            for (int pp = 0; pp < 5; ++pp) m[pp] = matS[pg * 5 + pp][cc];
            #pragma unroll
            for (int jj = 0; jj < 16; ++jj) {
                float wv = wS[jg * 16 + jj][cc];
                #pragma unroll
                for (int pp = 0; pp < 5; ++pp) acc[pp][jj] += m[pp] * wv;
            }
        }
        __syncthreads();
    }
    int j0 = jg * 16;
    u16* base = (j0 < 128) ? qws : kws;
    int jb = (j0 < 128) ? j0 : (j0 - 128);
    #pragma unroll
    for (int pp = 0; pp < 5; ++pp) {
        int p = pg * 5 + pp;
        size_t pix = (size_t)(b * 80 + a) * 80 + p;
        u32* dst = (u32*)(base + pix * 128 + jb);
        #pragma unroll
        for (int i = 0; i < 8; ++i) dst[i] = pack2(acc[pp][2 * i], acc[pp][2 * i + 1]);
    }
}

// ---------------- K1b: rotated Q/K projection (bilinear gather) ----------------
DEVI float tapx(const float* plane, int y, int x) {
    return (y >= 40 && y < 120 && x >= 40 && x < 120) ? plane[(y - 40) * 80 + (x - 40)] : 0.f;
}

__global__ __launch_bounds__(256) void k1_diag(const float* __restrict__ x,
                                               const float* __restrict__ Wi,
                                               const float* __restrict__ bi,
                                               u16* __restrict__ qws, u16* __restrict__ kws,
                                               float co, float si) {
    __shared__ float matS[80][17];
    __shared__ float wS[256][17];
    __shared__ int ix0[80], iy0[80];
    __shared__ float fwx[80], fwy[80];
    int t = threadIdx.x;
    int blk = blockIdx.x;
    int rot = blk / 640;
    int r2 = blk % 640;
    int b = r2 / 320;
    int r3 = r2 % 320;
    int a = r3 >> 1;
    int half = r3 & 1;
    int l0 = half * 80;
    float sir = rot ? -si : si;
    if (t < 80) {
        float dxx = (float)(l0 + t) - 79.5f, dyy = (float)a - 79.5f;
        float sx = co * dxx + sir * dyy + 79.5f;
        float sy = -sir * dxx + co * dyy + 79.5f;
        float x0 = floorf(sx), y0 = floorf(sy);
        ix0[t] = (int)x0; iy0[t] = (int)y0;
        fwx[t] = sx - x0; fwy[t] = sy - y0;
    }
    __syncthreads();
    int pg = t & 15, jg = t >> 4;
    float acc[5][16];
    #pragma unroll
    for (int jj = 0; jj < 16; ++jj) {
        float bv = bi[jg * 16 + jj];
        #pragma unroll
        for (int pp = 0; pp < 5; ++pp) acc[pp][jj] = bv;
    }
    for (int c0 = 0; c0 < 128; c0 += 16) {
        for (int idx = t; idx < 80 * 16; idx += 256) {
            int l = idx % 80, cc = idx / 80;
            const float* plane = x + (size_t)(b * 128 + c0 + cc) * 6400;
            int xx0 = ix0[l], yy0 = iy0[l];
            float wx = fwx[l], wy = fwy[l];
            float v00 = tapx(plane, yy0, xx0), v01 = tapx(plane, yy0, xx0 + 1);
            float v10 = tapx(plane, yy0 + 1, xx0), v11 = tapx(plane, yy0 + 1, xx0 + 1);
            matS[l][cc] = (1.f - wy) * ((1.f - wx) * v00 + wx * v01) +
                          wy * ((1.f - wx) * v10 + wx * v11);
        }
        {
            const float* wrow = Wi + t * 128 + c0;
            #pragma unroll
            for (int cc = 0; cc < 16; ++cc) wS[t][cc] = wrow[cc];
        }
        __syncthreads();
        #pragma unroll 4
        for (int cc = 0; cc < 16; ++cc) {
            float m[5];
            #pragma unroll
            for (int pp = 0; pp < 5; ++pp) m[pp] = matS[pg * 5 + pp][cc];
            #pragma unroll
            for (int jj = 0; jj < 16; ++jj) {
                float wv = wS[jg * 16 + jj][cc];
                #pragma unroll
                for (int pp = 0; pp < 5; ++pp) acc[pp][jj] += m[pp] * wv;
            }
        }
        __syncthreads();
    }
    int seqd = (rot * 2 + b) * 160 + a;
    size_t rowbase = (size_t)QD + (size_t)seqd * 160 * 128;
    int j0 = jg * 16;
    u16* base = (j0 < 128) ? qws : kws;
    int jb = (j0 < 128) ? j0 : (j0 - 128);
    #pragma unroll
    for (int pp = 0; pp < 5; ++pp) {
        int p = l0 + pg * 5 + pp;
        u32* dst = (u32*)(base + rowbase + (size_t)p * 128 + jb);
        #pragma unroll
        for (int i = 0; i < 8; ++i) dst[i] = pack2(acc[pp][2 * i], acc[pp][2 * i + 1]);
    }
}

// ---------------- K2: fused attention, all variants in ONE launch ----------------
// flat grid 2560: [0,1920) = VAR1 (chunk=flat/640, seq=flat%640)  [long blocks first]
//                 [1920,2560) = VAR0 (chunk=r/320, seq=r%320)
__global__ __launch_bounds__(256) void k_att_all(const u16* __restrict__ qws,
                                                 const u16* __restrict__ kws,
                                                 const float* __restrict__ wsf,
                                                 const u32* __restrict__ wotp,
                                                 const float* __restrict__ bo,
                                                 u16* __restrict__ rowres, u16* __restrict__ colres,
                                                 u16* __restrict__ rws, float co, float si) {
    __shared__ u32 oS[64 * 65];      // [64 rows][65] packed bf16 pairs (4 heads x 16)
    __shared__ float biasS[160];
    int t = threadIdx.x;
    int lane = t & 63;
    int hh = __builtin_amdgcn_readfirstlane(t >> 6);
    int flat = blockIdx.x;
    int VAR, chunk, seq;
    if (flat < 1920) { VAR = 1; chunk = flat / 640; seq = flat % 640; }
    else             { int r = flat - 1920; VAR = 0; chunk = r / 320; seq = r % 320; }
    int L = VAR ? 160 : 80;
    int c0 = chunk * 64;
    int CL = (L - c0 < 64) ? (L - c0) : 64;

    int b = 0, a = 0, isCol = 0, rot = 0, seqd = 0;
    if (VAR == 0) {
        isCol = (seq >= 160) ? 1 : 0;
        int r = seq - isCol * 160;
        b = r / 80; a = r % 80;
    } else {
        rot = seq / 320;
        int r = seq % 320;
        b = r / 160; a = r % 160;
        seqd = (rot * 2 + b) * 160 + a;
    }

    // mask bias (uniform over q-lanes; depends only on key index m)
    if (VAR == 1) {
        float sir = rot ? -si : si;
        float dyy = (float)a - 79.5f;
        if (t < 160) {
            float dxm = (float)t - 79.5f;
            float sx = co * dxm + sir * dyy + 79.5f;
            float sy = -sir * dxm + co * dyy + 79.5f;
            int xi = (int)rintf(sx), yi = (int)rintf(sy);
            biasS[t] = (xi >= 40 && xi < 120 && yi >= 40 && yi < 120) ? 1.0f : 0.0f;
        }
        __syncthreads();
    }

    // K addressing (global; wave-uniform address -> broadcast, L1/L2-served)
    const u16* kb;
    int kstep;
    if (VAR) { kb = kws + (size_t)QD + (size_t)seqd * 160 * 128 + hh * 32; kstep = 128; }
    else if (isCol) { kb = kws + (size_t)(b * 80 * 80 + a) * 128 + hh * 32; kstep = 80 * 128; }
    else { kb = kws + (size_t)((b * 80 + a) * 80) * 128 + hh * 32; kstep = 128; }

    // load my q row (packed bf16 -> f32x2 pairs)
    int l = c0 + lane;
    bool act = l < L;
    int lq = act ? l : (L - 1);
    size_t qoff;
    if (VAR) qoff = (size_t)QD + (size_t)(seqd * 160 + lq) * 128;
    else if (isCol) qoff = (size_t)((b * 80 + lq) * 80 + a) * 128;
    else qoff = (size_t)((b * 80 + a) * 80 + lq) * 128;
    f32x2 q2[16];
    {
        const uint4* qp = (const uint4*)(qws + qoff + hh * 32);
        uint4 w0 = qp[0], w1 = qp[1], w2 = qp[2], w3 = qp[3];
        u32 ww[16] = {w0.x, w0.y, w0.z, w0.w, w1.x, w1.y, w1.z, w1.w,
                      w2.x, w2.y, w2.z, w2.w, w3.x, w3.y, w3.z, w3.w};
        #pragma unroll
        for (int i = 0; i < 16; ++i) q2[i] = kpair(ww[i]);
    }

    const float* vbase = wsf + (VAR ? F_V160 : F_V80) + hh * L * 32;
    const float rs = 0.17677669529663687f;  // 1/sqrt(32)

    f32x2 o2[16];
    #pragma unroll
    for (int d = 0; d < 16; ++d) o2[d] = (f32x2){0.f, 0.f};
    float mrun = -3.0e38f, ssum = 0.f;

    uint4 kc0, kc1, kc2, kc3;
    {
        const uint4* kp = (const uint4*)kb;
        kc0 = kp[0]; kc1 = kp[1]; kc2 = kp[2]; kc3 = kp[3];
    }
    for (int m = 0; m < L; ++m) {
        uint4 kn0, kn1, kn2, kn3;
        if (m + 1 < L) {
            const uint4* kp = (const uint4*)(kb + (size_t)(m + 1) * kstep);
            kn0 = kp[0]; kn1 = kp[1]; kn2 = kp[2]; kn3 = kp[3];
        }
        u32 kw[16] = {kc0.x, kc0.y, kc0.z, kc0.w, kc1.x, kc1.y, kc1.z, kc1.w,
                      kc2.x, kc2.y, kc2.z, kc2.w, kc3.x, kc3.y, kc3.z, kc3.w};
        f32x2 s2 = (f32x2){0.f, 0.f};
        #pragma unroll
        for (int i = 0; i < 16; ++i) s2 += kpair(kw[i]) * q2[i];
        float s = (s2.x + s2.y) * rs;
        if (VAR) s += biasS[m];

        float p;
        if (s > mrun + 8.f) {  // defer-max
            float corr = __expf(mrun - s);
            f32x2 corr2 = (f32x2){corr, corr};
            ssum *= corr;
            #pragma unroll
            for (int d = 0; d < 16; ++d) o2[d] *= corr2;
            mrun = s;
            p = 1.f;
        } else {
            p = __expf(s - mrun);
        }
        ssum += p;
        const float4* vr4 = (const float4*)(vbase + (size_t)m * 32);
        f32x2 pv = (f32x2){p, p};
        #pragma unroll
        for (int i = 0; i < 8; ++i) {
            float4 vv = vr4[i];
            o2[2 * i]     += pv * (f32x2){vv.x, vv.y};
            o2[2 * i + 1] += pv * (f32x2){vv.z, vv.w};
        }
        kc0 = kn0; kc1 = kn1; kc2 = kn2; kc3 = kn3;
    }
    float inv = 1.f / ssum;
    if (act) {
        u32* dst = oS + lane * 65 + hh * 16;
        #pragma unroll
        for (int d = 0; d < 16; ++d) {
            f32x2 v = o2[d];
            dst[d] = pack2(v.x * inv, v.y * inv);
        }
    }
    __syncthreads();

    // epilogue: oo = o @ WoT + bo ; relative rotation ; store bf16
    const float* sinT = wsf + (VAR ? F_S160 : F_S80);
    const float* cosT = wsf + (VAR ? F_C160 : F_C80);
    int e = lane;
    int lw = t >> 6;
    for (int li = 0; li < 16; ++li) {
        int lp = lw * 16 + li;
        if (lp >= CL) break;
        f32x2 acc2 = (f32x2){bo[e], 0.f};
        const u32* orow = oS + lp * 65;
        #pragma unroll 8
        for (int jw = 0; jw < 64; ++jw) {
            acc2 += kpair(orow[jw]) * kpair(wotp[jw * 64 + e]);
        }
        float acc = acc2.x + acc2.y;
        int lg = c0 + lp;
        float sn = sinT[lg * 64 + (e >> 1)], cs = cosT[lg * 64 + (e >> 1)];
        float part = __shfl_xor(acc, 1);
        float r = (e & 1) ? (acc * cs + part * sn) : (acc * cs - part * sn);
        u16* dst;
        if (VAR) dst = rws + (size_t)((((rot * 2 + b) * 160 + a) * 160 + lg)) * 64;
        else if (isCol) dst = colres + (size_t)(((b * 80 + lg) * 80 + a)) * 64;
        else dst = rowres + (size_t)(((b * 80 + a) * 80 + lg)) * 64;
        dst[e] = f2bf(r);
    }
}

// ---------------- K3: rotate-back + elementwise sort + assemble ----------------
__global__ __launch_bounds__(256) void k3(const u16* __restrict__ rowres,
                                          const u16* __restrict__ colres,
                                          const u16* __restrict__ rws,
                                          float* __restrict__ out, float co, float si) {
    __shared__ float buf[40][257];
    int t = threadIdx.x;
    int blk = blockIdx.x;
    int b = blk / 160;
    int rem = blk % 160;
    int h = rem >> 1;
    int half = rem & 1;
    int w0 = half * 40;
    int e = t & 63, wv = t >> 6;
    for (int k = 0; k < 10; ++k) {
        int wl = wv * 10 + k;
        int w = w0 + wl;
        size_t pix = (size_t)(b * 80 + h) * 80 + w;
        float v0 = bf2f(rowres[pix * 64 + e]);
        float v1 = bf2f(colres[pix * 64 + e]);
        float dxx = (float)(w + 40) - 79.5f, dyy = (float)(h + 40) - 79.5f;
        float dvals[2];
        #pragma unroll
        for (int r = 0; r < 2; ++r) {
            float sirb = r ? si : -si;  // rotate-back angle = -ang
            float sx = co * dxx + sirb * dyy + 79.5f;
            float sy = -sirb * dxx + co * dyy + 79.5f;
            float x0 = floorf(sx), y0 = floorf(sy);
            int xi = (int)x0, yi = (int)y0;
            float wx = sx - x0, wy = sy - y0;
            const u16* rb = rws + (size_t)((r * 2 + b) * 160) * 160 * 64;
            float t00 = (yi >= 0 && yi < 160 && xi >= 0 && xi < 160) ? bf2f(rb[((size_t)yi * 160 + xi) * 64 + e]) : 0.f;
            float t01 = (yi >= 0 && yi < 160 && xi + 1 >= 0 && xi + 1 < 160) ? bf2f(rb[((size_t)yi * 160 + xi + 1) * 64 + e]) : 0.f;
            float t10 = (yi + 1 >= 0 && yi + 1 < 160 && xi >= 0 && xi < 160) ? bf2f(rb[((size_t)(yi + 1) * 160 + xi) * 64 + e]) : 0.f;
            float t11 = (yi + 1 >= 0 && yi + 1 < 160 && xi + 1 >= 0 && xi + 1 < 160) ? bf2f(rb[((size_t)(yi + 1) * 160 + xi + 1) * 64 + e]) : 0.f;
            dvals[r] = (1.f - wy) * ((1.f - wx) * t00 + wx * t01) + wy * ((1.f - wx) * t10 + wx * t11);
        }
        float a0 = v0, a1 = v1, a2 = dvals[0], a3 = dvals[1];
        float mn, mx;
        mn = fminf(a0, a1); mx = fmaxf(a0, a1); a0 = mn; a1 = mx;
        mn = fminf(a2, a3); mx = fmaxf(a2, a3); a2 = mn; a3 = mx;
        mn = fminf(a0, a2); mx = fmaxf(a0, a2); a0 = mn; a2 = mx;
        mn = fminf(a1, a3); mx = fmaxf(a1, a3); a1 = mn; a3 = mx;
        mn = fminf(a1, a2); mx = fmaxf(a1, a2); a1 = mn; a2 = mx;
        buf[wl][0 * 64 + e] = a0;
        buf[wl][1 * 64 + e] = a1;
        buf[wl][2 * 64 + e] = a2;
        buf[wl][3 * 64 + e] = a3;
    }
    __syncthreads();
    for (int idx = t; idx < 256 * 40; idx += 256) {
        int c = idx / 40, wl = idx % 40;
        out[(size_t)((b * 384 + 128 + c) * 80 + h) * 80 + w0 + wl] = buf[wl][c];
    }
}

// ---------------- x passthrough (channels 0..127) ----------------
__global__ void k_copy(const float* __restrict__ x, float* __restrict__ out) {
    int idx = blockIdx.x * 256 + threadIdx.x;
    if (idx < 409600) {
        float4 v = ((const float4*)x)[idx];
        int b = idx / 204800;
        int rem = idx % 204800;
        ((float4*)out)[(size_t)b * 614400 + rem] = v;
    }
}

extern "C" void kernel_launch(void* const* d_in, const int* in_sizes, int n_in,
                              void* d_out, int out_size, void* d_ws, size_t ws_size,
                              hipStream_t stream) {
    (void)in_sizes; (void)n_in; (void)out_size;
    const float* x  = (const float*)d_in[0];
    const float* Wi = (const float*)d_in[1];
    const float* bi = (const float*)d_in[2];
    const float* Wo = (const float*)d_in[3];
    const float* bo = (const float*)d_in[4];
    float* out = (float*)d_out;

    float* wsf = (float*)d_ws;
    u32* wotp = (u32*)(wsf + F_WOT);
    u16* wsb = (u16*)((char*)d_ws + FBYTES);
    u16* qws = wsb;
    u16* kws = wsb + (size_t)Q_SZ;
    u16* rws = kws + (size_t)Q_SZ;
    u16* rowres = rws + (size_t)RW_SZ;
    u16* colres = rowres + (size_t)RC_SZ;

    size_t need = FBYTES + ((size_t)Q_SZ * 2 + RW_SZ + RC_SZ * 2) * 2;
    if (ws_size < need) return;

    double th = 45.0 * M_PI / 180.0;
    float co = (float)cos(th), si = (float)sin(th);

    k_tables<<<dim3(240), dim3(128), 0, stream>>>(Wi, bi, wsf);
    k_wot<<<dim3(16), dim3(256), 0, stream>>>(Wo, wotp);
    k1_rc<<<dim3(160), dim3(256), 0, stream>>>(x, Wi, bi, qws, kws);
    k1_diag<<<dim3(1280), dim3(256), 0, stream>>>(x, Wi, bi, qws, kws, co, si);
    k_att_all<<<dim3(2560), dim3(256), 0, stream>>>(qws, kws, wsf, wotp, bo, rowres, colres, rws, co, si);
    k3<<<dim3(320), dim3(256), 0, stream>>>(rowres, colres, rws, out, co, si);
    k_copy<<<dim3(1600), dim3(256), 0, stream>>>(x, out);
}

// Round 6
// 348.903 us; speedup vs baseline: 3.4222x; 1.4904x over previous
//
#include <hip/hip_runtime.h>
#include <math.h>

#ifndef M_PI
#define M_PI 3.14159265358979323846
#endif

typedef unsigned int u32;
typedef unsigned short u16;
typedef float f32x2 __attribute__((ext_vector_type(2)));
typedef short bf16x8 __attribute__((ext_vector_type(8)));
typedef float f32x16 __attribute__((ext_vector_type(16)));

#define DEVI __device__ __forceinline__
#define MFMA32(a, b, c) __builtin_amdgcn_mfma_f32_32x32x16_bf16((a), (b), (c), 0, 0, 0)

// ---------------- geometry ----------------
// B=2, E=128, ENC=64, HEADS=4, DH=32, H=W=80, padded 160
constexpr int QD    = 12800 * 128;                 // diag q/k offset (bf16 elems)
constexpr int Q_SZ  = 12800 * 128 + 102400 * 128;  // 14,745,600
constexpr int QC_SZ = 12800 * 128;                 // col-major copies
constexpr int RW_SZ = 2 * 2 * 160 * 160 * 64;      // 6,553,600
constexpr int RC_SZ = 2 * 80 * 80 * 64;            // 819,200

// workspace byte offsets (table region)
constexpr size_t B_S80S  = 0;        // f32 [80][64] sin
constexpr size_t B_S80C  = 20480;    // f32 [80][64] cos
constexpr size_t B_S160S = 40960;    // f32 [160][64] sin
constexpr size_t B_S160C = 81920;    // f32 [160][64] cos
constexpr size_t B_VT80  = 122880;   // bf16 [4][32][96]  V^T (pad zero 80..95)
constexpr size_t B_VT160 = 147456;   // bf16 [4][32][160] V^T
constexpr size_t B_WO2   = 188416;   // bf16 [64][128]  Wo rows 0..63
constexpr size_t B_END   = 204800;

DEVI float bf2f(u16 h) { return __uint_as_float(((u32)h) << 16); }
DEVI u16 f2bf(float f) {
    u32 u = __float_as_uint(f);
    u32 r = (u + 0x7fffu + ((u >> 16) & 1u)) >> 16;
    return (u16)r;
}
DEVI u32 pack2(float lo, float hi) { return (u32)f2bf(lo) | ((u32)f2bf(hi) << 16); }

DEVI bf16x8 mkfrag(uint2 a, uint2 b) {
    union { bf16x8 f; u32 u[4]; } z;
    z.u[0] = a.x; z.u[1] = a.y; z.u[2] = b.x; z.u[3] = b.y;
    return z.f;
}
DEVI bf16x8 mkfrag4(u32 a, u32 b, u32 c, u32 d) {
    union { bf16x8 f; u32 u[4]; } z;
    z.u[0] = a; z.u[1] = b; z.u[2] = c; z.u[3] = d;
    return z.f;
}
DEVI u32 cvtpk(float lo, float hi) {
    u32 r;
    asm("v_cvt_pk_bf16_f32 %0, %1, %2" : "=v"(r) : "v"(lo), "v"(hi));
    return r;
}

// ---------------- K0: PE sin/cos tables + V^T bf16 tables ----------------
// grid MUST be 240: blk 0..79 -> L=80 table (l=blk); blk 80..239 -> L=160 table (l=blk-80).
__global__ void k_tables(const float* __restrict__ Wi, const float* __restrict__ bi,
                         char* __restrict__ ws) {
    int blk = blockIdx.x, t = threadIdx.x;
    bool is80 = blk < 80;
    int l = is80 ? blk : blk - 80;
    int M = is80 ? 96 : 160;
    float* sout = (float*)(ws + (is80 ? B_S80S : B_S160S));
    float* cout = (float*)(ws + (is80 ? B_S80C : B_S160C));
    u16* vt = (u16*)(ws + (is80 ? B_VT80 : B_VT160));
    __shared__ float P[128];
    if (t < 64) {
        float dv = powf(10000.f, (float)t / 64.f);
        float X = (float)(l + 1) / dv;
        float sv = sinf(X), cv = cosf(X);
        P[2 * t] = sv; P[2 * t + 1] = cv;
        sout[l * 64 + t] = sv; cout[l * 64 + t] = cv;
    }
    __syncthreads();
    float acc = bi[256 + t];
    #pragma unroll 16
    for (int c = 0; c < 128; ++c) acc += P[c] * Wi[(256 + t) * 128 + c];
    int hh = t >> 5, d = t & 31;
    vt[(hh * 32 + d) * M + l] = f2bf(acc);
    if (!is80 && blk < 96) {  // zero-pad vt80 cols 80..95
        u16* v8 = (u16*)(ws + B_VT80);
        v8[(hh * 32 + d) * 96 + blk] = 0;
    }
}

// ---------------- pack Wo (first 64 rows) to bf16 ----------------
__global__ void k_wot(const float* __restrict__ Wo, u16* __restrict__ wo2) {
    int idx = blockIdx.x * 256 + threadIdx.x;
    if (idx < 64 * 128) wo2[idx] = f2bf(Wo[idx]);
}

// ---------------- K1a: per-pixel Q/K projection (row+col shared) ----------------
__global__ __launch_bounds__(256) void k1_rc(const float* __restrict__ x,
                                             const float* __restrict__ Wi,
                                             const float* __restrict__ bi,
                                             u16* __restrict__ qws, u16* __restrict__ kws,
                                             u16* __restrict__ qcol, u16* __restrict__ kcol) {
    __shared__ float matS[80][17];
    __shared__ float wS[256][17];
    int t = threadIdx.x;
    int blk = blockIdx.x;
    int b = blk / 80, a = blk % 80;
    int pg = t & 15, jg = t >> 4;
    float acc[5][16];
    #pragma unroll
    for (int jj = 0; jj < 16; ++jj) {
        float bv = bi[jg * 16 + jj];
        #pragma unroll
        for (int pp = 0; pp < 5; ++pp) acc[pp][jj] = bv;
    }
    for (int c0 = 0; c0 < 128; c0 += 16) {
        for (int idx = t; idx < 80 * 16; idx += 256) {
            int l = idx % 80, cc = idx / 80;
            matS[l][cc] = x[(b * 128 + c0 + cc) * 6400 + a * 80 + l];
        }
        {
            const float* wrow = Wi + t * 128 + c0;
            #pragma unroll
            for (int cc = 0; cc < 16; ++cc) wS[t][cc] = wrow[cc];
        }
        __syncthreads();
        #pragma unroll 4
        for (int cc = 0; cc < 16; ++cc) {
            float m[5];
            #pragma unroll
            for (int pp = 0; pp < 5; ++pp) m[pp] = matS[pg * 5 + pp][cc];
            #pragma unroll
            for (int jj = 0; jj < 16; ++jj) {
                float wv = wS[jg * 16 + jj][cc];
                #pragma unroll
                for (int pp = 0; pp < 5; ++pp) acc[pp][jj] += m[pp] * wv;
            }
        }
        __syncthreads();
    }
    int j0 = jg * 16;
    bool isQ = (j0 < 128);
    float sc = isQ ? 0.17677669529663687f : 1.0f;  // q prescaled by 1/sqrt(32)
    u16* baser = isQ ? qws : kws;
    u16* basec = isQ ? qcol : kcol;
    int jb = isQ ? j0 : (j0 - 128);
    #pragma unroll
    for (int pp = 0; pp < 5; ++pp) {
        int p = pg * 5 + pp;
        size_t pixr = (size_t)(b * 80 + a) * 80 + p;      // [b][h=a][w=p]
        size_t pixc = (size_t)(b * 80 + p) * 80 + a;      // [b][w=p][h=a]
        u32 wv[8];
        #pragma unroll
        for (int i = 0; i < 8; ++i) wv[i] = pack2(acc[pp][2 * i] * sc, acc[pp][2 * i + 1] * sc);
        u32* dr = (u32*)(baser + pixr * 128 + jb);
        u32* dc = (u32*)(basec + pixc * 128 + jb);
        #pragma unroll
        for (int i = 0; i < 8; ++i) { dr[i] = wv[i]; dc[i] = wv[i]; }
    }
}

// ---------------- K1b: rotated Q/K projection (bilinear gather) ----------------
DEVI float tapx(const float* plane, int y, int x) {
    return (y >= 40 && y < 120 && x >= 40 && x < 120) ? plane[(y - 40) * 80 + (x - 40)] : 0.f;
}

__global__ __launch_bounds__(256) void k1_diag(const float* __restrict__ x,
                                               const float* __restrict__ Wi,
                                               const float* __restrict__ bi,
                                               u16* __restrict__ qws, u16* __restrict__ kws,
                                               float co, float si) {
    __shared__ float matS[80][17];
    __shared__ float wS[256][17];
    __shared__ int ix0[80], iy0[80];
    __shared__ float fwx[80], fwy[80];
    int t = threadIdx.x;
    int blk = blockIdx.x;
    int rot = blk / 640;
    int r2 = blk % 640;
    int b = r2 / 320;
    int r3 = r2 % 320;
    int a = r3 >> 1;
    int half = r3 & 1;
    int l0 = half * 80;
    float sir = rot ? -si : si;
    if (t < 80) {
        float dxx = (float)(l0 + t) - 79.5f, dyy = (float)a - 79.5f;
        float sx = co * dxx + sir * dyy + 79.5f;
        float sy = -sir * dxx + co * dyy + 79.5f;
        float x0 = floorf(sx), y0 = floorf(sy);
        ix0[t] = (int)x0; iy0[t] = (int)y0;
        fwx[t] = sx - x0; fwy[t] = sy - y0;
    }
    __syncthreads();
    int pg = t & 15, jg = t >> 4;
    float acc[5][16];
    #pragma unroll
    for (int jj = 0; jj < 16; ++jj) {
        float bv = bi[jg * 16 + jj];
        #pragma unroll
        for (int pp = 0; pp < 5; ++pp) acc[pp][jj] = bv;
    }
    for (int c0 = 0; c0 < 128; c0 += 16) {
        for (int idx = t; idx < 80 * 16; idx += 256) {
            int l = idx % 80, cc = idx / 80;
            const float* plane = x + (size_t)(b * 128 + c0 + cc) * 6400;
            int xx0 = ix0[l], yy0 = iy0[l];
            float wx = fwx[l], wy = fwy[l];
            float v00 = tapx(plane, yy0, xx0), v01 = tapx(plane, yy0, xx0 + 1);
            float v10 = tapx(plane, yy0 + 1, xx0), v11 = tapx(plane, yy0 + 1, xx0 + 1);
            matS[l][cc] = (1.f - wy) * ((1.f - wx) * v00 + wx * v01) +
                          wy * ((1.f - wx) * v10 + wx * v11);
        }
        {
            const float* wrow = Wi + t * 128 + c0;
            #pragma unroll
            for (int cc = 0; cc < 16; ++cc) wS[t][cc] = wrow[cc];
        }
        __syncthreads();
        #pragma unroll 4
        for (int cc = 0; cc < 16; ++cc) {
            float m[5];
            #pragma unroll
            for (int pp = 0; pp < 5; ++pp) m[pp] = matS[pg * 5 + pp][cc];
            #pragma unroll
            for (int jj = 0; jj < 16; ++jj) {
                float wv = wS[jg * 16 + jj][cc];
                #pragma unroll
                for (int pp = 0; pp < 5; ++pp) acc[pp][jj] += m[pp] * wv;
            }
        }
        __syncthreads();
    }
    int seqd = (rot * 2 + b) * 160 + a;
    size_t rowbase = (size_t)QD + (size_t)seqd * 160 * 128;
    int j0 = jg * 16;
    bool isQ = (j0 < 128);
    float sc = isQ ? 0.17677669529663687f : 1.0f;
    u16* base = isQ ? qws : kws;
    int jb = isQ ? j0 : (j0 - 128);
    #pragma unroll
    for (int pp = 0; pp < 5; ++pp) {
        int p = l0 + pg * 5 + pp;
        u32* dst = (u32*)(base + rowbase + (size_t)p * 128 + jb);
        #pragma unroll
        for (int i = 0; i < 8; ++i) dst[i] = pack2(acc[pp][2 * i] * sc, acc[pp][2 * i + 1] * sc);
    }
}

// ---------------- K2: MFMA fused attention ----------------
// grid 2560: flat<1920: VAR1 (qp=flat/640, seq=flat%640); else VAR0 (r=flat-1920, qp=r/320, seq=r%320)
// block = 4 waves = 4 heads; one 64-row q-pair per block.
template <int V>
DEVI void att_body(const char* __restrict__ ws, const float* __restrict__ bo,
                   float co, float si, int qp, int seq,
                   u16* __restrict__ oS, float* __restrict__ biasS) {
    constexpr int L  = V ? 160 : 80;
    constexpr int MT = V ? 5 : 3;
    constexpr int KC = V ? 10 : 6;
    int t = threadIdx.x;
    int lane = t & 63;
    int w = t >> 6;                       // wave = head
    int hh = __builtin_amdgcn_readfirstlane(w);
    int g = lane >> 5;
    int ln31 = lane & 31;

    const u16* qws  = (const u16*)(ws + B_END);
    const u16* kws  = qws + Q_SZ;
    const u16* qcol = kws + Q_SZ;
    const u16* kcol = qcol + QC_SZ;
    u16* rws    = (u16*)(ws + B_END) + (size_t)Q_SZ * 2 + (size_t)QC_SZ * 2;
    u16* rowres = rws + RW_SZ;
    u16* colres = rowres + RC_SZ;

    int b = 0, a = 0, isCol = 0, rot = 0, seqd = 0;
    const u16 *qb, *kb;
    if (V == 1) {
        rot = seq / 320;
        int r = seq % 320;
        b = r / 160; a = r % 160;
        seqd = (rot * 2 + b) * 160 + a;
        qb = qws + (size_t)QD + (size_t)seqd * 160 * 128;
        kb = kws + (size_t)QD + (size_t)seqd * 160 * 128;
    } else {
        isCol = (seq >= 160) ? 1 : 0;
        int r = seq - isCol * 160;
        b = r / 80; a = r % 80;
        size_t base = (size_t)(b * 80 + a) * 80 * 128;
        qb = (isCol ? qcol : qws) + base;
        kb = (isCol ? kcol : kws) + base;
    }

    // mask bias table (VAR1)
    if (V == 1) {
        float sir = rot ? -si : si;
        float dyy = (float)a - 79.5f;
        if (t < 160) {
            float dxm = (float)t - 79.5f;
            float sx = co * dxm + sir * dyy + 79.5f;
            float sy = -sir * dxm + co * dyy + 79.5f;
            int xi = (int)rintf(sx), yi = (int)rintf(sy);
            biasS[t] = (xi >= 40 && xi < 120 && yi >= 40 && yi < 120) ? 1.0f : 0.0f;
        }
        __syncthreads();
    }
    float bfr[MT];
    #pragma unroll
    for (int mt = 0; mt < MT; ++mt) {
        if (V == 1) bfr[mt] = biasS[ln31 + 32 * mt];
        else bfr[mt] = (mt == 2) ? ((ln31 + 64 < 80) ? 0.f : -30000.f) : 0.f;
    }
    bf16x8 onef = mkfrag4((g == 0) ? 0x3F80u : 0u, 0u, 0u, 0u);

    const u16* vt = (const u16*)(ws + (V ? B_VT160 : B_VT80));
    constexpr int M = V ? 160 : 96;
    const u16* vhead = vt + (size_t)hh * 32 * M;

    // ---- two q-chunks of 32 rows ----
    #pragma unroll
    for (int sub = 0; sub < 2; ++sub) {
        int c0 = qp * 64 + sub * 32;
        if (c0 >= L) continue;
        int l = c0 + ln31;
        int lq = (l < L) ? l : (L - 1);
        const u16* qr = qb + (size_t)lq * 128 + hh * 32;
        bf16x8 qf0 = mkfrag(*(const uint2*)(qr + 4 * g), *(const uint2*)(qr + 8 + 4 * g));
        bf16x8 qf1 = mkfrag(*(const uint2*)(qr + 16 + 4 * g), *(const uint2*)(qr + 24 + 4 * g));

        f32x16 acc[MT];
        #pragma unroll
        for (int mt = 0; mt < MT; ++mt)
            #pragma unroll
            for (int r = 0; r < 16; ++r) acc[mt][r] = 0.f;

        #pragma unroll
        for (int mt = 0; mt < MT; ++mt) {
            int mrow = 32 * mt + ln31;
            if (mrow > L - 1) mrow = L - 1;  // VAR0 pad clamp (benign elsewhere)
            const u16* kr = kb + (size_t)mrow * 128 + hh * 32;
            bf16x8 k0 = mkfrag(*(const uint2*)(kr + 4 * g), *(const uint2*)(kr + 8 + 4 * g));
            bf16x8 k1 = mkfrag(*(const uint2*)(kr + 16 + 4 * g), *(const uint2*)(kr + 24 + 4 * g));
            acc[mt] = MFMA32(k0, qf0, acc[mt]);
            acc[mt] = MFMA32(k1, qf1, acc[mt]);
            if (V == 1 || mt == 2) {  // bias chunk
                u32 ab = (g == 0) ? (u32)f2bf(bfr[mt]) : 0u;
                acc[mt] = MFMA32(mkfrag4(ab, 0u, 0u, 0u), onef, acc[mt]);
            }
        }

        // softmax over m (per-lane: own q-row = ln31; combine lane halves)
        float mx = -3.0e38f;
        #pragma unroll
        for (int mt = 0; mt < MT; ++mt)
            #pragma unroll
            for (int r = 0; r < 16; ++r) mx = fmaxf(mx, acc[mt][r]);
        mx = fmaxf(mx, __shfl_xor(mx, 32));
        float ssum = 0.f;
        #pragma unroll
        for (int mt = 0; mt < MT; ++mt)
            #pragma unroll
            for (int r = 0; r < 16; ++r) {
                float e = __expf(acc[mt][r] - mx);
                acc[mt][r] = e;
                ssum += e;
            }
        ssum += __shfl_xor(ssum, 32);
        float inv = __builtin_amdgcn_rcpf(ssum);
        #pragma unroll
        for (int mt = 0; mt < MT; ++mt)
            #pragma unroll
            for (int r = 0; r < 16; ++r) acc[mt][r] *= inv;

        // PV: O[l][d] += P[l][m] V[m][d]  (C->A direct register map)
        f32x16 O;
        #pragma unroll
        for (int r = 0; r < 16; ++r) O[r] = 0.f;
        #pragma unroll
        for (int kc = 0; kc < KC; ++kc) {
            int mt = kc >> 1, hb = (kc & 1) * 8;
            bf16x8 pa;
            {
                union { bf16x8 f; u32 u[4]; } z;
                z.u[0] = cvtpk(acc[mt][hb + 0], acc[mt][hb + 1]);
                z.u[1] = cvtpk(acc[mt][hb + 2], acc[mt][hb + 3]);
                z.u[2] = cvtpk(acc[mt][hb + 4], acc[mt][hb + 5]);
                z.u[3] = cvtpk(acc[mt][hb + 6], acc[mt][hb + 7]);
                pa = z.f;
            }
            const u16* vr = vhead + (size_t)ln31 * M + kc * 16 + 4 * g;
            bf16x8 vf = mkfrag(*(const uint2*)vr, *(const uint2*)(vr + 8));
            O = MFMA32(pa, vf, O);
        }

        // write O (bf16) into swizzled oS [64 rows][128 ch]
        #pragma unroll
        for (int r = 0; r < 16; ++r) {
            int row = sub * 32 + (r & 3) + 8 * (r >> 2) + 4 * g;
            u32 byteoff = (u32)(row * 256 + (hh * 32 + ln31) * 2) ^ (u32)((row & 7) << 4);
            *(u16*)((char*)oS + byteoff) = f2bf(O[r]);
        }
    }
    __syncthreads();

    // ---- epilogue: out = o @ Wo^T(64) + bo, relative-rotate, store ----
    int lt = w >> 1, et = w & 1;
    int e = et * 32 + ln31;
    int arow = lt * 32 + ln31;
    const u16* wo2 = (const u16*)(ws + B_WO2);
    f32x16 C;
    #pragma unroll
    for (int r = 0; r < 16; ++r) C[r] = 0.f;
    #pragma unroll
    for (int kc = 0; kc < 8; ++kc) {
        u32 ba = (u32)(arow * 256 + kc * 32 + 8 * g) ^ (u32)((arow & 7) << 4);
        u32 bb = (u32)(arow * 256 + kc * 32 + 8 * g + 16) ^ (u32)((arow & 7) << 4);
        bf16x8 af = mkfrag(*(const uint2*)((const char*)oS + ba),
                           *(const uint2*)((const char*)oS + bb));
        const u16* wr = wo2 + (size_t)e * 128 + kc * 16 + 4 * g;
        bf16x8 wf = mkfrag(*(const uint2*)wr, *(const uint2*)(wr + 8));
        C = MFMA32(af, wf, C);
    }
    float boe = bo[e];
    const float* sT = (const float*)(ws + (V ? B_S160S : B_S80S));
    const float* cT = (const float*)(ws + (V ? B_S160C : B_S80C));
    #pragma unroll
    for (int r = 0; r < 16; ++r) {
        int lg = qp * 64 + lt * 32 + (r & 3) + 8 * (r >> 2) + 4 * g;
        int lgc = (lg < L) ? lg : (L - 1);
        float v = C[r] + boe;
        float sn = sT[lgc * 64 + (e >> 1)], cs = cT[lgc * 64 + (e >> 1)];
        float part = __shfl_xor(v, 1);
        float res = (e & 1) ? (v * cs + part * sn) : (v * cs - part * sn);
        if (lg < L) {
            u16* dst;
            if (V == 1) dst = rws + (size_t)(seqd * 160 + lg) * 64;
            else if (isCol) dst = colres + (size_t)((b * 80 + lg) * 80 + a) * 64;
            else dst = rowres + (size_t)((b * 80 + a) * 80 + lg) * 64;
            dst[e] = f2bf(res);
        }
    }
}

__global__ __launch_bounds__(256, 2) void k_att_mfma(const char* __restrict__ ws,
                                                     const float* __restrict__ bo,
                                                     float co, float si) {
    __shared__ __align__(16) u16 oS[64 * 128];
    __shared__ float biasS[160];
    int flat = blockIdx.x;
    if (flat < 1920) {
        att_body<1>(ws, bo, co, si, flat / 640, flat % 640, oS, biasS);
    } else {
        int r = flat - 1920;
        att_body<0>(ws, bo, co, si, r / 320, r % 320, oS, biasS);
    }
}

// ---------------- K3: rotate-back + elementwise sort + assemble ----------------
__global__ __launch_bounds__(256) void k3(const u16* __restrict__ rowres,
                                          const u16* __restrict__ colres,
                                          const u16* __restrict__ rws,
                                          float* __restrict__ out, float co, float si) {
    __shared__ float buf[40][257];
    int t = threadIdx.x;
    int blk = blockIdx.x;
    int b = blk / 160;
    int rem = blk % 160;
    int h = rem >> 1;
    int half = rem & 1;
    int w0 = half * 40;
    int e = t & 63, wv = t >> 6;
    for (int k = 0; k < 10; ++k) {
        int wl = wv * 10 + k;
        int w = w0 + wl;
        size_t pix = (size_t)(b * 80 + h) * 80 + w;
        float v0 = bf2f(rowres[pix * 64 + e]);
        float v1 = bf2f(colres[pix * 64 + e]);
        float dxx = (float)(w + 40) - 79.5f, dyy = (float)(h + 40) - 79.5f;
        float dvals[2];
        #pragma unroll
        for (int r = 0; r < 2; ++r) {
            float sirb = r ? si : -si;  // rotate-back angle = -ang
            float sx = co * dxx + sirb * dyy + 79.5f;
            float sy = -sirb * dxx + co * dyy + 79.5f;
            float x0 = floorf(sx), y0 = floorf(sy);
            int xi = (int)x0, yi = (int)y0;
            float wx = sx - x0, wy = sy - y0;
            const u16* rb = rws + (size_t)((r * 2 + b) * 160) * 160 * 64;
            float t00 = (yi >= 0 && yi < 160 && xi >= 0 && xi < 160) ? bf2f(rb[((size_t)yi * 160 + xi) * 64 + e]) : 0.f;
            float t01 = (yi >= 0 && yi < 160 && xi + 1 >= 0 && xi + 1 < 160) ? bf2f(rb[((size_t)yi * 160 + xi + 1) * 64 + e]) : 0.f;
            float t10 = (yi + 1 >= 0 && yi + 1 < 160 && xi >= 0 && xi < 160) ? bf2f(rb[((size_t)(yi + 1) * 160 + xi) * 64 + e]) : 0.f;
            float t11 = (yi + 1 >= 0 && yi + 1 < 160 && xi + 1 >= 0 && xi + 1 < 160) ? bf2f(rb[((size_t)(yi + 1) * 160 + xi + 1) * 64 + e]) : 0.f;
            dvals[r] = (1.f - wy) * ((1.f - wx) * t00 + wx * t01) + wy * ((1.f - wx) * t10 + wx * t11);
        }
        float a0 = v0, a1 = v1, a2 = dvals[0], a3 = dvals[1];
        float mn, mx;
        mn = fminf(a0, a1); mx = fmaxf(a0, a1); a0 = mn; a1 = mx;
        mn = fminf(a2, a3); mx = fmaxf(a2, a3); a2 = mn; a3 = mx;
        mn = fminf(a0, a2); mx = fmaxf(a0, a2); a0 = mn; a2 = mx;
        mn = fminf(a1, a3); mx = fmaxf(a1, a3); a1 = mn; a3 = mx;
        mn = fminf(a1, a2); mx = fmaxf(a1, a2); a1 = mn; a2 = mx;
        buf[wl][0 * 64 + e] = a0;
        buf[wl][1 * 64 + e] = a1;
        buf[wl][2 * 64 + e] = a2;
        buf[wl][3 * 64 + e] = a3;
    }
    __syncthreads();
    for (int idx = t; idx < 256 * 40; idx += 256) {
        int c = idx / 40, wl = idx % 40;
        out[(size_t)((b * 384 + 128 + c) * 80 + h) * 80 + w0 + wl] = buf[wl][c];
    }
}

// ---------------- x passthrough (channels 0..127) ----------------
__global__ void k_copy(const float* __restrict__ x, float* __restrict__ out) {
    int idx = blockIdx.x * 256 + threadIdx.x;
    if (idx < 409600) {
        float4 v = ((const float4*)x)[idx];
        int b = idx / 204800;
        int rem = idx % 204800;
        ((float4*)out)[(size_t)b * 614400 + rem] = v;
    }
}

extern "C" void kernel_launch(void* const* d_in, const int* in_sizes, int n_in,
                              void* d_out, int out_size, void* d_ws, size_t ws_size,
                              hipStream_t stream) {
    (void)in_sizes; (void)n_in; (void)out_size;
    const float* x  = (const float*)d_in[0];
    const float* Wi = (const float*)d_in[1];
    const float* bi = (const float*)d_in[2];
    const float* Wo = (const float*)d_in[3];
    const float* bo = (const float*)d_in[4];
    float* out = (float*)d_out;

    char* ws = (char*)d_ws;
    u16* wo2  = (u16*)(ws + B_WO2);
    u16* qws  = (u16*)(ws + B_END);
    u16* kws  = qws + Q_SZ;
    u16* qcol = kws + Q_SZ;
    u16* kcol = qcol + QC_SZ;
    u16* rws  = kcol + QC_SZ;
    u16* rowres = rws + RW_SZ;
    u16* colres = rowres + RC_SZ;

    size_t need = B_END + ((size_t)Q_SZ * 2 + (size_t)QC_SZ * 2 + RW_SZ + (size_t)RC_SZ * 2) * 2;
    if (ws_size < need) return;

    double th = 45.0 * M_PI / 180.0;
    float co = (float)cos(th), si = (float)sin(th);

    k_tables<<<dim3(240), dim3(128), 0, stream>>>(Wi, bi, ws);   // 240! (80 + 160)
    k_wot<<<dim3(32), dim3(256), 0, stream>>>(Wo, wo2);
    k1_rc<<<dim3(160), dim3(256), 0, stream>>>(x, Wi, bi, qws, kws, qcol, kcol);
    k1_diag<<<dim3(1280), dim3(256), 0, stream>>>(x, Wi, bi, qws, kws, co, si);
    k_att_mfma<<<dim3(2560), dim3(256), 0, stream>>>(ws, bo, co, si);
    k3<<<dim3(320), dim3(256), 0, stream>>>(rowres, colres, rws, out, co, si);
    k_copy<<<dim3(1600), dim3(256), 0, stream>>>(x, out);
}

// Round 7
// 256.066 us; speedup vs baseline: 4.6629x; 1.3625x over previous
//
#include <hip/hip_runtime.h>
#include <math.h>

#ifndef M_PI
#define M_PI 3.14159265358979323846
#endif

typedef unsigned int u32;
typedef unsigned short u16;
typedef float f32x2 __attribute__((ext_vector_type(2)));
typedef short bf16x8 __attribute__((ext_vector_type(8)));
typedef float f32x16 __attribute__((ext_vector_type(16)));

#define DEVI __device__ __forceinline__
#define MFMA32(a, b, c) __builtin_amdgcn_mfma_f32_32x32x16_bf16((a), (b), (c), 0, 0, 0)

// ---------------- geometry ----------------
// B=2, E=128, ENC=64, HEADS=4, DH=32, H=W=80, padded 160
constexpr int QD    = 12800 * 128;                 // diag q/k offset (bf16 elems)
constexpr int Q_SZ  = 12800 * 128 + 102400 * 128;  // 14,745,600
constexpr int QC_SZ = 12800 * 128;                 // col-major copies
constexpr int RW_SZ = 2 * 2 * 160 * 160 * 64;      // 6,553,600
constexpr int RC_SZ = 2 * 80 * 80 * 64;            // 819,200

// workspace byte offsets (table region)
constexpr size_t B_S80S  = 0;        // f32 [80][64] sin
constexpr size_t B_S80C  = 20480;    // f32 [80][64] cos
constexpr size_t B_S160S = 40960;    // f32 [160][64] sin
constexpr size_t B_S160C = 81920;    // f32 [160][64] cos
constexpr size_t B_VT80  = 122880;   // bf16 [4][32][96]  V^T (pad zero 80..95)
constexpr size_t B_VT160 = 147456;   // bf16 [4][32][160] V^T
constexpr size_t B_WO2   = 188416;   // bf16 [64][128]  Wo rows 0..63
constexpr size_t B_END   = 204800;

DEVI float bf2f(u16 h) { return __uint_as_float(((u32)h) << 16); }
DEVI u16 f2bf(float f) {
    u32 u = __float_as_uint(f);
    u32 r = (u + 0x7fffu + ((u >> 16) & 1u)) >> 16;
    return (u16)r;
}
DEVI u32 pack2(float lo, float hi) { return (u32)f2bf(lo) | ((u32)f2bf(hi) << 16); }
DEVI f32x2 kpair(u32 w) {
    f32x2 r;
    r.x = __uint_as_float(w << 16);
    r.y = __uint_as_float(w & 0xffff0000u);
    return r;
}

DEVI bf16x8 mkfrag(uint2 a, uint2 b) {
    union { bf16x8 f; u32 u[4]; } z;
    z.u[0] = a.x; z.u[1] = a.y; z.u[2] = b.x; z.u[3] = b.y;
    return z.f;
}
DEVI bf16x8 mkfrag4(u32 a, u32 b, u32 c, u32 d) {
    union { bf16x8 f; u32 u[4]; } z;
    z.u[0] = a; z.u[1] = b; z.u[2] = c; z.u[3] = d;
    return z.f;
}
DEVI u32 cvtpk(float lo, float hi) {
    u32 r;
    asm("v_cvt_pk_bf16_f32 %0, %1, %2" : "=v"(r) : "v"(lo), "v"(hi));
    return r;
}

// ---------------- K0: PE sin/cos tables + V^T bf16 tables ----------------
// grid MUST be 240: blk 0..79 -> L=80 table (l=blk); blk 80..239 -> L=160 table (l=blk-80).
__global__ void k_tables(const float* __restrict__ Wi, const float* __restrict__ bi,
                         char* __restrict__ ws) {
    int blk = blockIdx.x, t = threadIdx.x;
    bool is80 = blk < 80;
    int l = is80 ? blk : blk - 80;
    int M = is80 ? 96 : 160;
    float* sout = (float*)(ws + (is80 ? B_S80S : B_S160S));
    float* cout = (float*)(ws + (is80 ? B_S80C : B_S160C));
    u16* vt = (u16*)(ws + (is80 ? B_VT80 : B_VT160));
    __shared__ float P[128];
    if (t < 64) {
        float dv = powf(10000.f, (float)t / 64.f);
        float X = (float)(l + 1) / dv;
        float sv = sinf(X), cv = cosf(X);
        P[2 * t] = sv; P[2 * t + 1] = cv;
        sout[l * 64 + t] = sv; cout[l * 64 + t] = cv;
    }
    __syncthreads();
    float acc = bi[256 + t];
    #pragma unroll 16
    for (int c = 0; c < 128; ++c) acc += P[c] * Wi[(256 + t) * 128 + c];
    int hh = t >> 5, d = t & 31;
    vt[(hh * 32 + d) * M + l] = f2bf(acc);
    if (!is80 && blk < 96) {  // zero-pad vt80 cols 80..95
        u16* v8 = (u16*)(ws + B_VT80);
        v8[(hh * 32 + d) * 96 + blk] = 0;
    }
}

// ---------------- pack Wo (first 64 rows) to bf16 ----------------
__global__ void k_wot(const float* __restrict__ Wo, u16* __restrict__ wo2) {
    int idx = blockIdx.x * 256 + threadIdx.x;
    if (idx < 64 * 128) wo2[idx] = f2bf(Wo[idx]);
}

// ---------------- K1a: per-pixel Q/K projection (row+col shared) ----------------
__global__ __launch_bounds__(256) void k1_rc(const float* __restrict__ x,
                                             const float* __restrict__ Wi,
                                             const float* __restrict__ bi,
                                             u16* __restrict__ qws, u16* __restrict__ kws,
                                             u16* __restrict__ qcol, u16* __restrict__ kcol) {
    __shared__ float matS[80][17];
    __shared__ float wS[256][17];
    int t = threadIdx.x;
    int blk = blockIdx.x;
    int b = blk / 80, a = blk % 80;
    int pg = t & 15, jg = t >> 4;
    float acc[5][16];
    #pragma unroll
    for (int jj = 0; jj < 16; ++jj) {
        float bv = bi[jg * 16 + jj];
        #pragma unroll
        for (int pp = 0; pp < 5; ++pp) acc[pp][jj] = bv;
    }
    for (int c0 = 0; c0 < 128; c0 += 16) {
        for (int idx = t; idx < 80 * 16; idx += 256) {
            int l = idx % 80, cc = idx / 80;
            matS[l][cc] = x[(b * 128 + c0 + cc) * 6400 + a * 80 + l];
        }
        {
            const float* wrow = Wi + t * 128 + c0;
            #pragma unroll
            for (int cc = 0; cc < 16; ++cc) wS[t][cc] = wrow[cc];
        }
        __syncthreads();
        #pragma unroll 4
        for (int cc = 0; cc < 16; ++cc) {
            float m[5];
            #pragma unroll
            for (int pp = 0; pp < 5; ++pp) m[pp] = matS[pg * 5 + pp][cc];
            #pragma unroll
            for (int jj = 0; jj < 16; ++jj) {
                float wv = wS[jg * 16 + jj][cc];
                #pragma unroll
                for (int pp = 0; pp < 5; ++pp) acc[pp][jj] += m[pp] * wv;
            }
        }
        __syncthreads();
    }
    int j0 = jg * 16;
    bool isQ = (j0 < 128);
    float sc = isQ ? 0.17677669529663687f : 1.0f;  // q prescaled by 1/sqrt(32)
    u16* baser = isQ ? qws : kws;
    u16* basec = isQ ? qcol : kcol;
    int jb = isQ ? j0 : (j0 - 128);
    #pragma unroll
    for (int pp = 0; pp < 5; ++pp) {
        int p = pg * 5 + pp;
        size_t pixr = (size_t)(b * 80 + a) * 80 + p;      // [b][h=a][w=p]
        size_t pixc = (size_t)(b * 80 + p) * 80 + a;      // [b][w=p][h=a]
        u32 wv[8];
        #pragma unroll
        for (int i = 0; i < 8; ++i) wv[i] = pack2(acc[pp][2 * i] * sc, acc[pp][2 * i + 1] * sc);
        u32* dr = (u32*)(baser + pixr * 128 + jb);
        u32* dc = (u32*)(basec + pixc * 128 + jb);
        #pragma unroll
        for (int i = 0; i < 8; ++i) { dr[i] = wv[i]; dc[i] = wv[i]; }
    }
}

// ---------------- K1b: rotated Q/K via bilinear interp of projected fields ----------------
// q_rot(p) = sum_taps w_i * q(tap_i) + (1 - wsum) * bias   (projection and interp commute)
// grid 2560 x 256; wave handles 10 pixels, lane = u32 channel-pair (64 = 128 bf16 ch).
__global__ __launch_bounds__(256) void k1_interp(const float* __restrict__ bi,
                                                 u16* __restrict__ qws, u16* __restrict__ kws,
                                                 float co, float si) {
    int t = threadIdx.x;
    int c = t & 63;
    int w = t >> 6;
    int W = blockIdx.x * 4 + w;
    const float sc = 0.17677669529663687f;
    f32x2 bq = {bi[2 * c] * sc, bi[2 * c + 1] * sc};
    f32x2 bk = {bi[128 + 2 * c], bi[128 + 2 * c + 1]};
    const u32* qsrc = (const u32*)qws;
    const u32* ksrc = (const u32*)kws;
    u32* qdst = (u32*)qws + (size_t)QD / 2;
    u32* kdst = (u32*)kws + (size_t)QD / 2;

    #pragma unroll 2
    for (int i = 0; i < 10; ++i) {
        int pix = W * 10 + i;
        int seqd = pix / 160;
        int p = pix % 160;
        int rot = seqd / 320;
        int a = seqd % 160;
        int b = (seqd / 160) & 1;
        float sir = rot ? -si : si;
        float dxx = (float)p - 79.5f, dyy = (float)a - 79.5f;
        float sx = co * dxx + sir * dyy + 79.5f;
        float sy = -sir * dxx + co * dyy + 79.5f;
        float x0f = floorf(sx), y0f = floorf(sy);
        int x0 = (int)x0f, y0 = (int)y0f;
        float wx = sx - x0f, wy = sy - y0f;
        float wt[4] = {(1.f - wy) * (1.f - wx), (1.f - wy) * wx, wy * (1.f - wx), wy * wx};
        int ty[4] = {y0, y0, y0 + 1, y0 + 1};
        int tx[4] = {x0, x0 + 1, x0, x0 + 1};
        f32x2 qa = {0.f, 0.f}, ka = {0.f, 0.f};
        float wsum = 0.f;
        #pragma unroll
        for (int k = 0; k < 4; ++k) {
            int yy = ty[k], xx = tx[k];
            if (yy >= 40 && yy < 120 && xx >= 40 && xx < 120) {
                size_t src = ((size_t)(b * 80 + (yy - 40)) * 80 + (xx - 40)) * 64 + c;
                f32x2 wv = {wt[k], wt[k]};
                qa += wv * kpair(qsrc[src]);
                ka += wv * kpair(ksrc[src]);
                wsum += wt[k];
            }
        }
        float rem = 1.f - wsum;
        f32x2 rem2 = {rem, rem};
        qa += rem2 * bq;
        ka += rem2 * bk;
        size_t dst = (size_t)(seqd * 160 + p) * 64 + c;
        qdst[dst] = pack2(qa.x, qa.y);
        kdst[dst] = pack2(ka.x, ka.y);
    }
}

// ---------------- K2: MFMA fused attention ----------------
// grid 2560: flat<1920: VAR1 (qp=flat/640, seq=flat%640); else VAR0 (r=flat-1920, qp=r/320, seq=r%320)
// block = 4 waves = 4 heads; one 64-row q-pair per block.
template <int V>
DEVI void att_body(const char* __restrict__ ws, const float* __restrict__ bo,
                   float co, float si, int qp, int seq,
                   u16* __restrict__ oS, float* __restrict__ biasS) {
    constexpr int L  = V ? 160 : 80;
    constexpr int MT = V ? 5 : 3;
    constexpr int KC = V ? 10 : 6;
    int t = threadIdx.x;
    int lane = t & 63;
    int w = t >> 6;                       // wave = head
    int hh = __builtin_amdgcn_readfirstlane(w);
    int g = lane >> 5;
    int ln31 = lane & 31;

    const u16* qws  = (const u16*)(ws + B_END);
    const u16* kws  = qws + Q_SZ;
    const u16* qcol = kws + Q_SZ;
    const u16* kcol = qcol + QC_SZ;
    u16* rws    = (u16*)(ws + B_END) + (size_t)Q_SZ * 2 + (size_t)QC_SZ * 2;
    u16* rowres = rws + RW_SZ;
    u16* colres = rowres + RC_SZ;

    int b = 0, a = 0, isCol = 0, rot = 0, seqd = 0;
    const u16 *qb, *kb;
    if (V == 1) {
        rot = seq / 320;
        int r = seq % 320;
        b = r / 160; a = r % 160;
        seqd = (rot * 2 + b) * 160 + a;
        qb = qws + (size_t)QD + (size_t)seqd * 160 * 128;
        kb = kws + (size_t)QD + (size_t)seqd * 160 * 128;
    } else {
        isCol = (seq >= 160) ? 1 : 0;
        int r = seq - isCol * 160;
        b = r / 80; a = r % 80;
        size_t base = (size_t)(b * 80 + a) * 80 * 128;
        qb = (isCol ? qcol : qws) + base;
        kb = (isCol ? kcol : kws) + base;
    }

    // mask bias table (VAR1)
    if (V == 1) {
        float sir = rot ? -si : si;
        float dyy = (float)a - 79.5f;
        if (t < 160) {
            float dxm = (float)t - 79.5f;
            float sx = co * dxm + sir * dyy + 79.5f;
            float sy = -sir * dxm + co * dyy + 79.5f;
            int xi = (int)rintf(sx), yi = (int)rintf(sy);
            biasS[t] = (xi >= 40 && xi < 120 && yi >= 40 && yi < 120) ? 1.0f : 0.0f;
        }
        __syncthreads();
    }
    float bfr[MT];
    #pragma unroll
    for (int mt = 0; mt < MT; ++mt) {
        if (V == 1) bfr[mt] = biasS[ln31 + 32 * mt];
        else bfr[mt] = (mt == 2) ? ((ln31 + 64 < 80) ? 0.f : -30000.f) : 0.f;
    }
    bf16x8 onef = mkfrag4((g == 0) ? 0x3F80u : 0u, 0u, 0u, 0u);

    const u16* vt = (const u16*)(ws + (V ? B_VT160 : B_VT80));
    constexpr int M = V ? 160 : 96;
    const u16* vhead = vt + (size_t)hh * 32 * M;

    // ---- two q-chunks of 32 rows ----
    #pragma unroll
    for (int sub = 0; sub < 2; ++sub) {
        int c0 = qp * 64 + sub * 32;
        if (c0 >= L) continue;
        int l = c0 + ln31;
        int lq = (l < L) ? l : (L - 1);
        const u16* qr = qb + (size_t)lq * 128 + hh * 32;
        bf16x8 qf0 = mkfrag(*(const uint2*)(qr + 4 * g), *(const uint2*)(qr + 8 + 4 * g));
        bf16x8 qf1 = mkfrag(*(const uint2*)(qr + 16 + 4 * g), *(const uint2*)(qr + 24 + 4 * g));

        f32x16 acc[MT];
        #pragma unroll
        for (int mt = 0; mt < MT; ++mt)
            #pragma unroll
            for (int r = 0; r < 16; ++r) acc[mt][r] = 0.f;

        #pragma unroll
        for (int mt = 0; mt < MT; ++mt) {
            int mrow = 32 * mt + ln31;
            if (mrow > L - 1) mrow = L - 1;  // VAR0 pad clamp (benign elsewhere)
            const u16* kr = kb + (size_t)mrow * 128 + hh * 32;
            bf16x8 k0 = mkfrag(*(const uint2*)(kr + 4 * g), *(const uint2*)(kr + 8 + 4 * g));
            bf16x8 k1 = mkfrag(*(const uint2*)(kr + 16 + 4 * g), *(const uint2*)(kr + 24 + 4 * g));
            acc[mt] = MFMA32(k0, qf0, acc[mt]);
            acc[mt] = MFMA32(k1, qf1, acc[mt]);
            if (V == 1 || mt == 2) {  // bias chunk
                u32 ab = (g == 0) ? (u32)f2bf(bfr[mt]) : 0u;
                acc[mt] = MFMA32(mkfrag4(ab, 0u, 0u, 0u), onef, acc[mt]);
            }
        }

        // softmax over m (per-lane: own q-row = ln31; combine lane halves)
        float mx = -3.0e38f;
        #pragma unroll
        for (int mt = 0; mt < MT; ++mt)
            #pragma unroll
            for (int r = 0; r < 16; ++r) mx = fmaxf(mx, acc[mt][r]);
        mx = fmaxf(mx, __shfl_xor(mx, 32));
        float ssum = 0.f;
        #pragma unroll
        for (int mt = 0; mt < MT; ++mt)
            #pragma unroll
            for (int r = 0; r < 16; ++r) {
                float e = __expf(acc[mt][r] - mx);
                acc[mt][r] = e;
                ssum += e;
            }
        ssum += __shfl_xor(ssum, 32);
        float inv = __builtin_amdgcn_rcpf(ssum);
        #pragma unroll
        for (int mt = 0; mt < MT; ++mt)
            #pragma unroll
            for (int r = 0; r < 16; ++r) acc[mt][r] *= inv;

        // PV: O[l][d] += P[l][m] V[m][d]  (C->A direct register map)
        f32x16 O;
        #pragma unroll
        for (int r = 0; r < 16; ++r) O[r] = 0.f;
        #pragma unroll
        for (int kc = 0; kc < KC; ++kc) {
            int mt = kc >> 1, hb = (kc & 1) * 8;
            bf16x8 pa;
            {
                union { bf16x8 f; u32 u[4]; } z;
                z.u[0] = cvtpk(acc[mt][hb + 0], acc[mt][hb + 1]);
                z.u[1] = cvtpk(acc[mt][hb + 2], acc[mt][hb + 3]);
                z.u[2] = cvtpk(acc[mt][hb + 4], acc[mt][hb + 5]);
                z.u[3] = cvtpk(acc[mt][hb + 6], acc[mt][hb + 7]);
                pa = z.f;
            }
            const u16* vr = vhead + (size_t)ln31 * M + kc * 16 + 4 * g;
            bf16x8 vf = mkfrag(*(const uint2*)vr, *(const uint2*)(vr + 8));
            O = MFMA32(pa, vf, O);
        }

        // write O (bf16) into swizzled oS [64 rows][128 ch]
        #pragma unroll
        for (int r = 0; r < 16; ++r) {
            int row = sub * 32 + (r & 3) + 8 * (r >> 2) + 4 * g;
            u32 byteoff = (u32)(row * 256 + (hh * 32 + ln31) * 2) ^ (u32)((row & 7) << 4);
            *(u16*)((char*)oS + byteoff) = f2bf(O[r]);
        }
    }
    __syncthreads();

    // ---- epilogue: out = o @ Wo^T(64) + bo, relative-rotate, store ----
    int lt = w >> 1, et = w & 1;
    int e = et * 32 + ln31;
    int arow = lt * 32 + ln31;
    const u16* wo2 = (const u16*)(ws + B_WO2);
    f32x16 C;
    #pragma unroll
    for (int r = 0; r < 16; ++r) C[r] = 0.f;
    #pragma unroll
    for (int kc = 0; kc < 8; ++kc) {
        u32 ba = (u32)(arow * 256 + kc * 32 + 8 * g) ^ (u32)((arow & 7) << 4);
        u32 bb = (u32)(arow * 256 + kc * 32 + 8 * g + 16) ^ (u32)((arow & 7) << 4);
        bf16x8 af = mkfrag(*(const uint2*)((const char*)oS + ba),
                           *(const uint2*)((const char*)oS + bb));
        const u16* wr = wo2 + (size_t)e * 128 + kc * 16 + 4 * g;
        bf16x8 wf = mkfrag(*(const uint2*)wr, *(const uint2*)(wr + 8));
        C = MFMA32(af, wf, C);
    }
    float boe = bo[e];
    const float* sT = (const float*)(ws + (V ? B_S160S : B_S80S));
    const float* cT = (const float*)(ws + (V ? B_S160C : B_S80C));
    #pragma unroll
    for (int r = 0; r < 16; ++r) {
        int lg = qp * 64 + lt * 32 + (r & 3) + 8 * (r >> 2) + 4 * g;
        int lgc = (lg < L) ? lg : (L - 1);
        float v = C[r] + boe;
        float sn = sT[lgc * 64 + (e >> 1)], cs = cT[lgc * 64 + (e >> 1)];
        float part = __shfl_xor(v, 1);
        float res = (e & 1) ? (v * cs + part * sn) : (v * cs - part * sn);
        if (lg < L) {
            u16* dst;
            if (V == 1) dst = rws + (size_t)(seqd * 160 + lg) * 64;
            else if (isCol) dst = colres + (size_t)((b * 80 + lg) * 80 + a) * 64;
            else dst = rowres + (size_t)((b * 80 + a) * 80 + lg) * 64;
            dst[e] = f2bf(res);
        }
    }
}

__global__ __launch_bounds__(256, 2) void k_att_mfma(const char* __restrict__ ws,
                                                     const float* __restrict__ bo,
                                                     float co, float si) {
    __shared__ __align__(16) u16 oS[64 * 128];
    __shared__ float biasS[160];
    int flat = blockIdx.x;
    if (flat < 1920) {
        att_body<1>(ws, bo, co, si, flat / 640, flat % 640, oS, biasS);
    } else {
        int r = flat - 1920;
        att_body<0>(ws, bo, co, si, r / 320, r % 320, oS, biasS);
    }
}

// ---------------- K3: rotate-back + elementwise sort + assemble ----------------
__global__ __launch_bounds__(256) void k3(const u16* __restrict__ rowres,
                                          const u16* __restrict__ colres,
                                          const u16* __restrict__ rws,
                                          float* __restrict__ out, float co, float si) {
    __shared__ float buf[40][257];
    int t = threadIdx.x;
    int blk = blockIdx.x;
    int b = blk / 160;
    int rem = blk % 160;
    int h = rem >> 1;
    int half = rem & 1;
    int w0 = half * 40;
    int e = t & 63, wv = t >> 6;
    for (int k = 0; k < 10; ++k) {
        int wl = wv * 10 + k;
        int w = w0 + wl;
        size_t pix = (size_t)(b * 80 + h) * 80 + w;
        float v0 = bf2f(rowres[pix * 64 + e]);
        float v1 = bf2f(colres[pix * 64 + e]);
        float dxx = (float)(w + 40) - 79.5f, dyy = (float)(h + 40) - 79.5f;
        float dvals[2];
        #pragma unroll
        for (int r = 0; r < 2; ++r) {
            float sirb = r ? si : -si;  // rotate-back angle = -ang
            float sx = co * dxx + sirb * dyy + 79.5f;
            float sy = -sirb * dxx + co * dyy + 79.5f;
            float x0 = floorf(sx), y0 = floorf(sy);
            int xi = (int)x0, yi = (int)y0;
            float wx = sx - x0, wy = sy - y0;
            const u16* rb = rws + (size_t)((r * 2 + b) * 160) * 160 * 64;
            float t00 = (yi >= 0 && yi < 160 && xi >= 0 && xi < 160) ? bf2f(rb[((size_t)yi * 160 + xi) * 64 + e]) : 0.f;
            float t01 = (yi >= 0 && yi < 160 && xi + 1 >= 0 && xi + 1 < 160) ? bf2f(rb[((size_t)yi * 160 + xi + 1) * 64 + e]) : 0.f;
            float t10 = (yi + 1 >= 0 && yi + 1 < 160 && xi >= 0 && xi < 160) ? bf2f(rb[((size_t)(yi + 1) * 160 + xi) * 64 + e]) : 0.f;
            float t11 = (yi + 1 >= 0 && yi + 1 < 160 && xi + 1 >= 0 && xi + 1 < 160) ? bf2f(rb[((size_t)(yi + 1) * 160 + xi + 1) * 64 + e]) : 0.f;
            dvals[r] = (1.f - wy) * ((1.f - wx) * t00 + wx * t01) + wy * ((1.f - wx) * t10 + wx * t11);
        }
        float a0 = v0, a1 = v1, a2 = dvals[0], a3 = dvals[1];
        float mn, mx;
        mn = fminf(a0, a1); mx = fmaxf(a0, a1); a0 = mn; a1 = mx;
        mn = fminf(a2, a3); mx = fmaxf(a2, a3); a2 = mn; a3 = mx;
        mn = fminf(a0, a2); mx = fmaxf(a0, a2); a0 = mn; a2 = mx;
        mn = fminf(a1, a3); mx = fmaxf(a1, a3); a1 = mn; a3 = mx;
        mn = fminf(a1, a2); mx = fmaxf(a1, a2); a1 = mn; a2 = mx;
        buf[wl][0 * 64 + e] = a0;
        buf[wl][1 * 64 + e] = a1;
        buf[wl][2 * 64 + e] = a2;
        buf[wl][3 * 64 + e] = a3;
    }
    __syncthreads();
    for (int idx = t; idx < 256 * 40; idx += 256) {
        int c = idx / 40, wl = idx % 40;
        out[(size_t)((b * 384 + 128 + c) * 80 + h) * 80 + w0 + wl] = buf[wl][c];
    }
}

// ---------------- x passthrough (channels 0..127) ----------------
__global__ void k_copy(const float* __restrict__ x, float* __restrict__ out) {
    int idx = blockIdx.x * 256 + threadIdx.x;
    if (idx < 409600) {
        float4 v = ((const float4*)x)[idx];
        int b = idx / 204800;
        int rem = idx % 204800;
        ((float4*)out)[(size_t)b * 614400 + rem] = v;
    }
}

extern "C" void kernel_launch(void* const* d_in, const int* in_sizes, int n_in,
                              void* d_out, int out_size, void* d_ws, size_t ws_size,
                              hipStream_t stream) {
    (void)in_sizes; (void)n_in; (void)out_size;
    const float* x  = (const float*)d_in[0];
    const float* Wi = (const float*)d_in[1];
    const float* bi = (const float*)d_in[2];
    const float* Wo = (const float*)d_in[3];
    const float* bo = (const float*)d_in[4];
    float* out = (float*)d_out;

    char* ws = (char*)d_ws;
    u16* wo2  = (u16*)(ws + B_WO2);
    u16* qws  = (u16*)(ws + B_END);
    u16* kws  = qws + Q_SZ;
    u16* qcol = kws + Q_SZ;
    u16* kcol = qcol + QC_SZ;
    u16* rws  = kcol + QC_SZ;
    u16* rowres = rws + RW_SZ;
    u16* colres = rowres + RC_SZ;

    size_t need = B_END + ((size_t)Q_SZ * 2 + (size_t)QC_SZ * 2 + RW_SZ + (size_t)RC_SZ * 2) * 2;
    if (ws_size < need) return;

    double th = 45.0 * M_PI / 180.0;
    float co = (float)cos(th), si = (float)sin(th);

    k_tables<<<dim3(240), dim3(128), 0, stream>>>(Wi, bi, ws);   // 240! (80 + 160)
    k_wot<<<dim3(32), dim3(256), 0, stream>>>(Wo, wo2);
    k1_rc<<<dim3(160), dim3(256), 0, stream>>>(x, Wi, bi, qws, kws, qcol, kcol);
    k1_interp<<<dim3(2560), dim3(256), 0, stream>>>(bi, qws, kws, co, si);
    k_att_mfma<<<dim3(2560), dim3(256), 0, stream>>>(ws, bo, co, si);
    k3<<<dim3(320), dim3(256), 0, stream>>>(rowres, colres, rws, out, co, si);
    k_copy<<<dim3(1600), dim3(256), 0, stream>>>(x, out);
}

// Round 8
// 226.305 us; speedup vs baseline: 5.2761x; 1.1315x over previous
//
#include <hip/hip_runtime.h>
#include <math.h>

#ifndef M_PI
#define M_PI 3.14159265358979323846
#endif

typedef unsigned int u32;
typedef unsigned short u16;
typedef float f32x2 __attribute__((ext_vector_type(2)));
typedef short bf16x8 __attribute__((ext_vector_type(8)));
typedef float f32x16 __attribute__((ext_vector_type(16)));

#define DEVI __device__ __forceinline__
#define MFMA32(a, b, c) __builtin_amdgcn_mfma_f32_32x32x16_bf16((a), (b), (c), 0, 0, 0)

// ---------------- geometry ----------------
// B=2, E=128, ENC=64, HEADS=4, DH=32, H=W=80, padded 160
constexpr int    QR_SZ   = 12800 * 128;            // row-major q/k field (u16)
constexpr size_t QTD_U32 = (size_t)640 * 5 * 2048; // diag tiles: 640 seq x 5 chunk x 4head x 16slot x 32lane
constexpr int    RW_SZ   = 2 * 2 * 160 * 160 * 64;
constexpr int    RC_SZ   = 2 * 80 * 80 * 64;

// u16-unit offsets after B_END
constexpr size_t O_QWS  = 0;
constexpr size_t O_KWS  = QR_SZ;
constexpr size_t O_QCOL = 2 * (size_t)QR_SZ;
constexpr size_t O_KCOL = 3 * (size_t)QR_SZ;
constexpr size_t O_QTD  = 4 * (size_t)QR_SZ;          // u32 region (u16 units)
constexpr size_t O_KTD  = O_QTD + 2 * QTD_U32;
constexpr size_t O_RWS  = O_KTD + 2 * QTD_U32;
constexpr size_t O_ROW  = O_RWS + RW_SZ;
constexpr size_t O_COL  = O_ROW + RC_SZ;
constexpr size_t O_END  = O_COL + RC_SZ;

// table-region byte offsets
constexpr size_t B_S80S  = 0;        // f32 [80][64] sin
constexpr size_t B_S80C  = 20480;
constexpr size_t B_S160S = 40960;    // f32 [160][64]
constexpr size_t B_S160C = 81920;
constexpr size_t B_VT80  = 122880;   // u32 tiles [4][6][8][32]  (24KB)
constexpr size_t B_VT160 = 147456;   // u32 tiles [4][10][8][32] (40KB)
constexpr size_t B_WO2   = 188416;   // u32 tiles [2][8][8][32]  (16KB)
constexpr size_t B_END   = 204800;

DEVI float bf2f(u16 h) { return __uint_as_float(((u32)h) << 16); }
DEVI u16 f2bf(float f) {
    u32 u = __float_as_uint(f);
    u32 r = (u + 0x7fffu + ((u >> 16) & 1u)) >> 16;
    return (u16)r;
}
DEVI u32 pack2(float lo, float hi) { return (u32)f2bf(lo) | ((u32)f2bf(hi) << 16); }
DEVI f32x2 kpair(u32 w) {
    f32x2 r;
    r.x = __uint_as_float(w << 16);
    r.y = __uint_as_float(w & 0xffff0000u);
    return r;
}
DEVI bf16x8 mkfrag(uint2 a, uint2 b) {
    union { bf16x8 f; u32 u[4]; } z;
    z.u[0] = a.x; z.u[1] = a.y; z.u[2] = b.x; z.u[3] = b.y;
    return z.f;
}
DEVI bf16x8 mkfrag4(u32 a, u32 b, u32 c, u32 d) {
    union { bf16x8 f; u32 u[4]; } z;
    z.u[0] = a; z.u[1] = b; z.u[2] = c; z.u[3] = d;
    return z.f;
}
DEVI u32 cvtpk(float lo, float hi) {
    u32 r;
    asm("v_cvt_pk_bf16_f32 %0, %1, %2" : "=v"(r) : "v"(lo), "v"(hi));
    return r;
}

// slot math (HW-verified frag layout): within a 16-channel group, channel offset o16:
//   g=(o16>>2)&1, jl=(o16>>1)&1, hi=o16>>3, half=o16&1; slot S=hi*4+jl*2+g
// frag u32[j] (j: hi=j>>1, jl=j&1) lives at tile[S(j,g)*32 + ln31] = tile[j*64 + lane].

// ---------------- K0: PE sin/cos tables + V tiles ----------------
// grid 240: blk<80 -> L=80 tables; blk 80..239 -> L=160 (l=blk-80); blk 80..95 also zero-pads VT80.
__global__ void k_tables(const float* __restrict__ Wi, const float* __restrict__ bi,
                         char* __restrict__ ws) {
    int blk = blockIdx.x, t = threadIdx.x;
    bool is80 = blk < 80;
    int l = is80 ? blk : blk - 80;
    int KC = is80 ? 6 : 10;
    float* sout = (float*)(ws + (is80 ? B_S80S : B_S160S));
    float* cout = (float*)(ws + (is80 ? B_S80C : B_S160C));
    u32* vt = (u32*)(ws + (is80 ? B_VT80 : B_VT160));
    __shared__ float P[128];
    if (t < 64) {
        float dv = powf(10000.f, (float)t / 64.f);
        float X = (float)(l + 1) / dv;
        float sv = sinf(X), cv = cosf(X);
        P[2 * t] = sv; P[2 * t + 1] = cv;
        sout[l * 64 + t] = sv; cout[l * 64 + t] = cv;
    }
    __syncthreads();
    float acc = bi[256 + t];
    #pragma unroll 16
    for (int c = 0; c < 128; ++c) acc += P[c] * Wi[(256 + t) * 128 + c];
    int hh = t >> 5, d = t & 31;
    {
        int m = l, kc = m >> 4, o16 = m & 15;
        int g = (o16 >> 2) & 1, jl = (o16 >> 1) & 1, hi = o16 >> 3, half = o16 & 1;
        int S = hi * 4 + jl * 2 + g;
        ((u16*)(vt + ((size_t)(hh * KC + kc) * 8 + S) * 32 + d))[half] = f2bf(acc);
    }
    if (!is80 && blk < 96) {  // zero-pad VT80 rows 80..95
        u32* v8 = (u32*)(ws + B_VT80);
        int m = blk, kc = m >> 4, o16 = m & 15;
        int g = (o16 >> 2) & 1, jl = (o16 >> 1) & 1, hi = o16 >> 3, half = o16 & 1;
        int S = hi * 4 + jl * 2 + g;
        ((u16*)(v8 + ((size_t)(hh * 6 + kc) * 8 + S) * 32 + d))[half] = 0;
    }
}

// ---------------- Wo tiles [et][kc][S][lane] ----------------
__global__ void k_wot(const float* __restrict__ Wo, u32* __restrict__ wt) {
    int idx = blockIdx.x * 256 + threadIdx.x;
    if (idx < 64 * 64) {
        int e = idx >> 6, p = idx & 63;
        int ch = 2 * p;
        int kc = ch >> 4, o16 = ch & 15;
        int g = (o16 >> 2) & 1, jl = (o16 >> 1) & 1, hi = o16 >> 3;
        int S = hi * 4 + jl * 2 + g;
        int et = e >> 5, lane = e & 31;
        wt[((size_t)(et * 8 + kc) * 8 + S) * 32 + lane] =
            pack2(Wo[e * 128 + ch], Wo[e * 128 + ch + 1]);
    }
}

// ---------------- K1a: per-pixel Q/K projection (row+col shared) ----------------
__global__ __launch_bounds__(256) void k1_rc(const float* __restrict__ x,
                                             const float* __restrict__ Wi,
                                             const float* __restrict__ bi,
                                             u16* __restrict__ qws, u16* __restrict__ kws,
                                             u16* __restrict__ qcol, u16* __restrict__ kcol) {
    __shared__ float matS[80][17];
    __shared__ float wS[256][17];
    int t = threadIdx.x;
    int blk = blockIdx.x;
    int b = blk / 80, a = blk % 80;
    int pg = t & 15, jg = t >> 4;
    float acc[5][16];
    #pragma unroll
    for (int jj = 0; jj < 16; ++jj) {
        float bv = bi[jg * 16 + jj];
        #pragma unroll
        for (int pp = 0; pp < 5; ++pp) acc[pp][jj] = bv;
    }
    for (int c0 = 0; c0 < 128; c0 += 16) {
        for (int idx = t; idx < 80 * 16; idx += 256) {
            int l = idx % 80, cc = idx / 80;
            matS[l][cc] = x[(b * 128 + c0 + cc) * 6400 + a * 80 + l];
        }
        {
            const float* wrow = Wi + t * 128 + c0;
            #pragma unroll
            for (int cc = 0; cc < 16; ++cc) wS[t][cc] = wrow[cc];
        }
        __syncthreads();
        #pragma unroll 4
        for (int cc = 0; cc < 16; ++cc) {
            float m[5];
            #pragma unroll
            for (int pp = 0; pp < 5; ++pp) m[pp] = matS[pg * 5 + pp][cc];
            #pragma unroll
            for (int jj = 0; jj < 16; ++jj) {
                float wv = wS[jg * 16 + jj][cc];
                #pragma unroll
                for (int pp = 0; pp < 5; ++pp) acc[pp][jj] += m[pp] * wv;
            }
        }
        __syncthreads();
    }
    int j0 = jg * 16;
    bool isQ = (j0 < 128);
    float sc = isQ ? 0.17677669529663687f : 1.0f;  // q prescaled by 1/sqrt(32)
    u16* baser = isQ ? qws : kws;
    u16* basec = isQ ? qcol : kcol;
    int jb = isQ ? j0 : (j0 - 128);
    #pragma unroll
    for (int pp = 0; pp < 5; ++pp) {
        int p = pg * 5 + pp;
        size_t pixr = (size_t)(b * 80 + a) * 80 + p;
        size_t pixc = (size_t)(b * 80 + p) * 80 + a;
        u32 wv[8];
        #pragma unroll
        for (int i = 0; i < 8; ++i) wv[i] = pack2(acc[pp][2 * i] * sc, acc[pp][2 * i + 1] * sc);
        u32* dr = (u32*)(baser + pixr * 128 + jb);
        u32* dc = (u32*)(basec + pixc * 128 + jb);
        #pragma unroll
        for (int i = 0; i < 8; ++i) { dr[i] = wv[i]; dc[i] = wv[i]; }
    }
}

// ---------------- K1b: rotated Q/K interp -> fragment tiles ----------------
// grid 3200 = 640 seq x 5 chunks; 4 waves x 8 pixels; lane = u32 channel-pair.
__global__ __launch_bounds__(256) void k1_interp(const float* __restrict__ bi,
                                                 const u16* __restrict__ qws,
                                                 const u16* __restrict__ kws,
                                                 u32* __restrict__ qtd, u32* __restrict__ ktd,
                                                 float co, float si) {
    __shared__ u32 qS[32][65];
    __shared__ u32 kS[32][65];
    int t = threadIdx.x;
    int c = t & 63;
    int w = t >> 6;
    int bid = blockIdx.x;
    int seqd = bid / 5, chunk = bid % 5;
    int rot = seqd / 320;
    int a = seqd % 160;
    int b = (seqd / 160) & 1;
    float sir = rot ? -si : si;
    const float sc = 0.17677669529663687f;
    f32x2 bq = {bi[2 * c] * sc, bi[2 * c + 1] * sc};
    f32x2 bk = {bi[128 + 2 * c], bi[128 + 2 * c + 1]};
    const u32* qsrc = (const u32*)qws;
    const u32* ksrc = (const u32*)kws;
    float dyy = (float)a - 79.5f;

    for (int i = 0; i < 8; ++i) {
        int lp = w * 8 + i;
        int p = chunk * 32 + lp;
        float dxx = (float)p - 79.5f;
        float sx = co * dxx + sir * dyy + 79.5f;
        float sy = -sir * dxx + co * dyy + 79.5f;
        float x0f = floorf(sx), y0f = floorf(sy);
        int x0 = (int)x0f, y0 = (int)y0f;
        float wx = sx - x0f, wy = sy - y0f;
        float wt[4] = {(1.f - wy) * (1.f - wx), (1.f - wy) * wx, wy * (1.f - wx), wy * wx};
        int ty[4] = {y0, y0, y0 + 1, y0 + 1};
        int tx[4] = {x0, x0 + 1, x0, x0 + 1};
        f32x2 qa = {0.f, 0.f}, ka = {0.f, 0.f};
        float wsum = 0.f;
        #pragma unroll
        for (int k = 0; k < 4; ++k) {
            int yy = ty[k], xx = tx[k];
            if (yy >= 40 && yy < 120 && xx >= 40 && xx < 120) {
                size_t src = ((size_t)(b * 80 + (yy - 40)) * 80 + (xx - 40)) * 64 + c;
                f32x2 wv = {wt[k], wt[k]};
                qa += wv * kpair(qsrc[src]);
                ka += wv * kpair(ksrc[src]);
                wsum += wt[k];
            }
        }
        float rem = 1.f - wsum;
        f32x2 rem2 = {rem, rem};
        qa += rem2 * bq;
        ka += rem2 * bk;
        qS[lp][c] = pack2(qa.x, qa.y);
        kS[lp][c] = pack2(ka.x, ka.y);
    }
    __syncthreads();
    // permute-repack: 128 slot-cols (2 fields x 4 heads x 16 S16) x 32 lanes
    size_t tbase = (size_t)bid * 2048;
    int lane = t & 31;
    #pragma unroll
    for (int it = 0; it < 16; ++it) {
        int scol = it * 8 + (t >> 5);
        int field = scol >> 6;
        int head = (scol >> 4) & 3;
        int S16 = scol & 15;
        int fr = S16 >> 3, s = S16 & 7;
        int g = s & 1, jl = (s >> 1) & 1, hi = s >> 2;
        int p2 = head * 16 + fr * 8 + hi * 4 + g * 2 + jl;
        u32 v = field ? kS[lane][p2] : qS[lane][p2];
        u32* dst = (field ? ktd : qtd) + tbase + (size_t)(head * 16 + S16) * 32 + lane;
        *dst = v;
    }
}

// ---------------- K2: MFMA fused attention ----------------
template <int V>
DEVI void att_body(const char* __restrict__ ws, const float* __restrict__ bo,
                   float co, float si, int qp, int seq,
                   u16* __restrict__ oS, float* __restrict__ biasS) {
    constexpr int L  = V ? 160 : 80;
    constexpr int MT = V ? 5 : 3;
    constexpr int KC = V ? 10 : 6;
    int t = threadIdx.x;
    int lane = t & 63;
    int w = t >> 6;
    int hh = __builtin_amdgcn_readfirstlane(w);
    int g = lane >> 5;
    int ln31 = lane & 31;

    const u16* wsb  = (const u16*)(ws + B_END);
    const u16* qws  = wsb + O_QWS;
    const u16* kws  = wsb + O_KWS;
    const u16* qcol = wsb + O_QCOL;
    const u16* kcol = wsb + O_KCOL;
    const u32* qtd  = (const u32*)(wsb + O_QTD);
    const u32* ktd  = (const u32*)(wsb + O_KTD);
    u16* rws    = (u16*)(wsb + O_RWS);
    u16* rowres = (u16*)(wsb + O_ROW);
    u16* colres = (u16*)(wsb + O_COL);

    int b = 0, a = 0, isCol = 0, rot = 0, seqd = 0;
    const u16 *qb = nullptr, *kb = nullptr;
    if (V == 1) {
        rot = seq / 320;
        int r = seq % 320;
        b = r / 160; a = r % 160;
        seqd = (rot * 2 + b) * 160 + a;
    } else {
        isCol = (seq >= 160) ? 1 : 0;
        int r = seq - isCol * 160;
        b = r / 80; a = r % 80;
        size_t base = (size_t)(b * 80 + a) * 80 * 128;
        qb = (isCol ? qcol : qws) + base;
        kb = (isCol ? kcol : kws) + base;
    }

    if (V == 1) {
        float sir = rot ? -si : si;
        float dyy = (float)a - 79.5f;
        if (t < 160) {
            float dxm = (float)t - 79.5f;
            float sx = co * dxm + sir * dyy + 79.5f;
            float sy = -sir * dxm + co * dyy + 79.5f;
            int xi = (int)rintf(sx), yi = (int)rintf(sy);
            biasS[t] = (xi >= 40 && xi < 120 && yi >= 40 && yi < 120) ? 1.0f : 0.0f;
        }
        __syncthreads();
    }
    float bfr[MT];
    #pragma unroll
    for (int mt = 0; mt < MT; ++mt) {
        if (V == 1) bfr[mt] = biasS[ln31 + 32 * mt];
        else bfr[mt] = (mt == 2) ? ((ln31 + 64 < 80) ? 0.f : -30000.f) : 0.f;
    }
    bf16x8 onef = mkfrag4((g == 0) ? 0x3F80u : 0u, 0u, 0u, 0u);

    const u32* vt32 = (const u32*)(ws + (V ? B_VT160 : B_VT80));
    const u32* vhead = vt32 + (size_t)hh * KC * 256;

    #pragma unroll
    for (int sub = 0; sub < 2; ++sub) {
        int c0 = qp * 64 + sub * 32;
        if (c0 >= L) continue;
        bf16x8 qf0, qf1;
        if (V == 1) {
            const u32* qtb = qtd + (size_t)(seqd * 5 + (qp * 2 + sub)) * 2048 + (size_t)hh * 512;
            qf0 = mkfrag4(qtb[lane], qtb[64 + lane], qtb[128 + lane], qtb[192 + lane]);
            qf1 = mkfrag4(qtb[256 + lane], qtb[320 + lane], qtb[384 + lane], qtb[448 + lane]);
        } else {
            int l = c0 + ln31;
            int lq = (l < L) ? l : (L - 1);
            const u16* qr = qb + (size_t)lq * 128 + hh * 32;
            qf0 = mkfrag(*(const uint2*)(qr + 4 * g), *(const uint2*)(qr + 8 + 4 * g));
            qf1 = mkfrag(*(const uint2*)(qr + 16 + 4 * g), *(const uint2*)(qr + 24 + 4 * g));
        }

        f32x16 acc[MT];
        #pragma unroll
        for (int mt = 0; mt < MT; ++mt)
            #pragma unroll
            for (int r = 0; r < 16; ++r) acc[mt][r] = 0.f;

        #pragma unroll
        for (int mt = 0; mt < MT; ++mt) {
            bf16x8 k0, k1;
            if (V == 1) {
                const u32* ktb = ktd + (size_t)(seqd * 5 + mt) * 2048 + (size_t)hh * 512;
                k0 = mkfrag4(ktb[lane], ktb[64 + lane], ktb[128 + lane], ktb[192 + lane]);
                k1 = mkfrag4(ktb[256 + lane], ktb[320 + lane], ktb[384 + lane], ktb[448 + lane]);
            } else {
                int mrow = 32 * mt + ln31;
                if (mrow > L - 1) mrow = L - 1;
                const u16* kr = kb + (size_t)mrow * 128 + hh * 32;
                k0 = mkfrag(*(const uint2*)(kr + 4 * g), *(const uint2*)(kr + 8 + 4 * g));
                k1 = mkfrag(*(const uint2*)(kr + 16 + 4 * g), *(const uint2*)(kr + 24 + 4 * g));
            }
            acc[mt] = MFMA32(k0, qf0, acc[mt]);
            acc[mt] = MFMA32(k1, qf1, acc[mt]);
            if (V == 1 || mt == 2) {
                u32 ab = (g == 0) ? (u32)f2bf(bfr[mt]) : 0u;
                acc[mt] = MFMA32(mkfrag4(ab, 0u, 0u, 0u), onef, acc[mt]);
            }
        }

        // softmax (per-lane q-row; combine lane halves)
        float mx = -3.0e38f;
        #pragma unroll
        for (int mt = 0; mt < MT; ++mt)
            #pragma unroll
            for (int r = 0; r < 16; ++r) mx = fmaxf(mx, acc[mt][r]);
        mx = fmaxf(mx, __shfl_xor(mx, 32));
        float ssum = 0.f;
        #pragma unroll
        for (int mt = 0; mt < MT; ++mt)
            #pragma unroll
            for (int r = 0; r < 16; ++r) {
                float e = __expf(acc[mt][r] - mx);
                acc[mt][r] = e;
                ssum += e;
            }
        ssum += __shfl_xor(ssum, 32);
        float inv = __builtin_amdgcn_rcpf(ssum);
        #pragma unroll
        for (int mt = 0; mt < MT; ++mt)
            #pragma unroll
            for (int r = 0; r < 16; ++r) acc[mt][r] *= inv;

        // PV (C->A direct register map), V from tiles
        f32x16 O;
        #pragma unroll
        for (int r = 0; r < 16; ++r) O[r] = 0.f;
        #pragma unroll
        for (int kc = 0; kc < KC; ++kc) {
            int mt = kc >> 1, hb = (kc & 1) * 8;
            bf16x8 pa;
            {
                union { bf16x8 f; u32 u[4]; } z;
                z.u[0] = cvtpk(acc[mt][hb + 0], acc[mt][hb + 1]);
                z.u[1] = cvtpk(acc[mt][hb + 2], acc[mt][hb + 3]);
                z.u[2] = cvtpk(acc[mt][hb + 4], acc[mt][hb + 5]);
                z.u[3] = cvtpk(acc[mt][hb + 6], acc[mt][hb + 7]);
                pa = z.f;
            }
            const u32* vtb = vhead + (size_t)kc * 256;
            bf16x8 vf = mkfrag4(vtb[lane], vtb[64 + lane], vtb[128 + lane], vtb[192 + lane]);
            O = MFMA32(pa, vf, O);
        }

        // O -> swizzled oS (8B-granular 16-slot XOR)
        #pragma unroll
        for (int r = 0; r < 16; ++r) {
            int row = sub * 32 + (r & 3) + 8 * (r >> 2) + 4 * g;
            u32 byteoff = ((u32)(row * 256 + (hh * 32 + ln31) * 2)) ^ ((u32)(row & 15) << 3);
            *(u16*)((char*)oS + byteoff) = f2bf(O[r]);
        }
    }
    __syncthreads();

    // ---- epilogue: out = o @ Wo^T(64) + bo, relative-rotate, store ----
    int lt = w >> 1, et = w & 1;
    int e = et * 32 + ln31;
    int arow = lt * 32 + ln31;
    const u32* wt32 = (const u32*)(ws + B_WO2);
    f32x16 C;
    #pragma unroll
    for (int r = 0; r < 16; ++r) C[r] = 0.f;
    #pragma unroll
    for (int kc = 0; kc < 8; ++kc) {
        u32 xsw = (u32)(arow & 15) << 3;
        u32 ba = ((u32)(arow * 256 + kc * 32 + 8 * g)) ^ xsw;
        u32 bb = ((u32)(arow * 256 + kc * 32 + 8 * g + 16)) ^ xsw;
        bf16x8 af = mkfrag(*(const uint2*)((const char*)oS + ba),
                           *(const uint2*)((const char*)oS + bb));
        const u32* wtb = wt32 + (size_t)(et * 8 + kc) * 256;
        bf16x8 wf = mkfrag4(wtb[lane], wtb[64 + lane], wtb[128 + lane], wtb[192 + lane]);
        C = MFMA32(af, wf, C);
    }
    float boe = bo[e];
    const float* sT = (const float*)(ws + (V ? B_S160S : B_S80S));
    const float* cT = (const float*)(ws + (V ? B_S160C : B_S80C));
    #pragma unroll
    for (int r = 0; r < 16; ++r) {
        int lg = qp * 64 + lt * 32 + (r & 3) + 8 * (r >> 2) + 4 * g;
        int lgc = (lg < L) ? lg : (L - 1);
        float v = C[r] + boe;
        float sn = sT[lgc * 64 + (e >> 1)], cs = cT[lgc * 64 + (e >> 1)];
        float part = __shfl_xor(v, 1);
        float res = (e & 1) ? (v * cs + part * sn) : (v * cs - part * sn);
        if (lg < L) {
            u16* dst;
            if (V == 1) dst = rws + (size_t)(seqd * 160 + lg) * 64;
            else if (isCol) dst = colres + (size_t)((b * 80 + lg) * 80 + a) * 64;
            else dst = rowres + (size_t)((b * 80 + a) * 80 + lg) * 64;
            dst[e] = f2bf(res);
        }
    }
}

__global__ __launch_bounds__(256, 2) void k_att_mfma(const char* __restrict__ ws,
                                                     const float* __restrict__ bo,
                                                     float co, float si) {
    __shared__ __align__(16) u16 oS[64 * 128];
    __shared__ float biasS[160];
    int flat = blockIdx.x;
    if (flat < 1920) {
        att_body<1>(ws, bo, co, si, flat / 640, flat % 640, oS, biasS);
    } else {
        int r = flat - 1920;
        att_body<0>(ws, bo, co, si, r / 320, r % 320, oS, biasS);
    }
}

// ---------------- K3: rotate-back + elementwise sort + assemble ----------------
__global__ __launch_bounds__(256) void k3(const u16* __restrict__ rowres,
                                          const u16* __restrict__ colres,
                                          const u16* __restrict__ rws,
                                          float* __restrict__ out, float co, float si) {
    __shared__ float buf[40][257];
    int t = threadIdx.x;
    int blk = blockIdx.x;
    int b = blk / 160;
    int rem = blk % 160;
    int h = rem >> 1;
    int half = rem & 1;
    int w0 = half * 40;
    int e = t & 63, wv = t >> 6;
    for (int k = 0; k < 10; ++k) {
        int wl = wv * 10 + k;
        int w = w0 + wl;
        size_t pix = (size_t)(b * 80 + h) * 80 + w;
        float v0 = bf2f(rowres[pix * 64 + e]);
        float v1 = bf2f(colres[pix * 64 + e]);
        float dxx = (float)(w + 40) - 79.5f, dyy = (float)(h + 40) - 79.5f;
        float dvals[2];
        #pragma unroll
        for (int r = 0; r < 2; ++r) {
            float sirb = r ? si : -si;
            float sx = co * dxx + sirb * dyy + 79.5f;
            float sy = -sirb * dxx + co * dyy + 79.5f;
            float x0 = floorf(sx), y0 = floorf(sy);
            int xi = (int)x0, yi = (int)y0;
            float wx = sx - x0, wy = sy - y0;
            const u16* rb = rws + (size_t)((r * 2 + b) * 160) * 160 * 64;
            float t00 = (yi >= 0 && yi < 160 && xi >= 0 && xi < 160) ? bf2f(rb[((size_t)yi * 160 + xi) * 64 + e]) : 0.f;
            float t01 = (yi >= 0 && yi < 160 && xi + 1 >= 0 && xi + 1 < 160) ? bf2f(rb[((size_t)yi * 160 + xi + 1) * 64 + e]) : 0.f;
            float t10 = (yi + 1 >= 0 && yi + 1 < 160 && xi >= 0 && xi < 160) ? bf2f(rb[((size_t)(yi + 1) * 160 + xi) * 64 + e]) : 0.f;
            float t11 = (yi + 1 >= 0 && yi + 1 < 160 && xi + 1 >= 0 && xi + 1 < 160) ? bf2f(rb[((size_t)(yi + 1) * 160 + xi + 1) * 64 + e]) : 0.f;
            dvals[r] = (1.f - wy) * ((1.f - wx) * t00 + wx * t01) + wy * ((1.f - wx) * t10 + wx * t11);
        }
        float a0 = v0, a1 = v1, a2 = dvals[0], a3 = dvals[1];
        float mn, mx;
        mn = fminf(a0, a1); mx = fmaxf(a0, a1); a0 = mn; a1 = mx;
        mn = fminf(a2, a3); mx = fmaxf(a2, a3); a2 = mn; a3 = mx;
        mn = fminf(a0, a2); mx = fmaxf(a0, a2); a0 = mn; a2 = mx;
        mn = fminf(a1, a3); mx = fmaxf(a1, a3); a1 = mn; a3 = mx;
        mn = fminf(a1, a2); mx = fmaxf(a1, a2); a1 = mn; a2 = mx;
        buf[wl][0 * 64 + e] = a0;
        buf[wl][1 * 64 + e] = a1;
        buf[wl][2 * 64 + e] = a2;
        buf[wl][3 * 64 + e] = a3;
    }
    __syncthreads();
    for (int idx = t; idx < 256 * 40; idx += 256) {
        int c = idx / 40, wl = idx % 40;
        out[(size_t)((b * 384 + 128 + c) * 80 + h) * 80 + w0 + wl] = buf[wl][c];
    }
}

// ---------------- x passthrough ----------------
__global__ void k_copy(const float* __restrict__ x, float* __restrict__ out) {
    int idx = blockIdx.x * 256 + threadIdx.x;
    if (idx < 409600) {
        float4 v = ((const float4*)x)[idx];
        int b = idx / 204800;
        int rem = idx % 204800;
        ((float4*)out)[(size_t)b * 614400 + rem] = v;
    }
}

extern "C" void kernel_launch(void* const* d_in, const int* in_sizes, int n_in,
                              void* d_out, int out_size, void* d_ws, size_t ws_size,
                              hipStream_t stream) {
    (void)in_sizes; (void)n_in; (void)out_size;
    const float* x  = (const float*)d_in[0];
    const float* Wi = (const float*)d_in[1];
    const float* bi = (const float*)d_in[2];
    const float* Wo = (const float*)d_in[3];
    const float* bo = (const float*)d_in[4];
    float* out = (float*)d_out;

    char* ws = (char*)d_ws;
    u32* wt   = (u32*)(ws + B_WO2);
    u16* wsb  = (u16*)(ws + B_END);
    u16* qws  = wsb + O_QWS;
    u16* kws  = wsb + O_KWS;
    u16* qcol = wsb + O_QCOL;
    u16* kcol = wsb + O_KCOL;
    u32* qtd  = (u32*)(wsb + O_QTD);
    u32* ktd  = (u32*)(wsb + O_KTD);
    u16* rowres = wsb + O_ROW;
    u16* colres = wsb + O_COL;
    u16* rws    = wsb + O_RWS;

    size_t need = B_END + O_END * 2;
    if (ws_size < need) return;

    double th = 45.0 * M_PI / 180.0;
    float co = (float)cos(th), si = (float)sin(th);

    k_tables<<<dim3(240), dim3(128), 0, stream>>>(Wi, bi, ws);
    k_wot<<<dim3(16), dim3(256), 0, stream>>>(Wo, wt);
    k1_rc<<<dim3(160), dim3(256), 0, stream>>>(x, Wi, bi, qws, kws, qcol, kcol);
    k1_interp<<<dim3(3200), dim3(256), 0, stream>>>(bi, qws, kws, qtd, ktd, co, si);
    k_att_mfma<<<dim3(2560), dim3(256), 0, stream>>>(ws, bo, co, si);
    k3<<<dim3(320), dim3(256), 0, stream>>>(rowres, colres, rws, out, co, si);
    k_copy<<<dim3(1600), dim3(256), 0, stream>>>(x, out);
}